// Round 1
// baseline (11449.714 us; speedup 1.0000x reference)
//
#include <hip/hip_runtime.h>
#include <math.h>

// MLA baseline: fp32 everywhere (CDNA4 has no fp32 MFMA; this is a vector-ALU
// correctness-first implementation; bf16 MFMA is the round-2 experiment).
//
// Pipeline (all on `stream`, sequential deps):
//  1. c_q      = X @ Wq_lr^T + b          [2048,1536]
//  2. q_cont   = c_q @ Wq_c^T + b   -> qb [s, h*192 + 0..127]   (scatter mode)
//  3. qrope    = c_q @ Wq_rope^T+b  -> fb [2048,2048]
//     rope_scatter_q: rope over full 2048 dim -> qb [s, h*192 + 128..191]
//  4. c_kv     = X @ Wkv^T + b            [2048,512]
//  5. k_cont   = c_kv @ Wk_c^T + b  -> kb (scatter mode)
//  6. krope    = X @ Wk_rope^T + b  -> fb [2048,64]
//     rope_bcast_k: rope over 64 dim, broadcast to all 32 heads -> kb
//  7. v        = c_kv @ Wv^T + b          [2048,4096]  (layout == [s,h*128+d])
//  8. rmsnorm rows of qb, kb (192-dim per (s,h), eps = FLT_EPSILON)
//  9. flash attention (BQ=16, BKV=32, online softmax, additive mask) -> fb
// 10. out      = fb @ Wo^T + bo
//
// Workspace: c_q(12.6M) + c_kv(4.2M) + qb(50.3M) + kb(50.3M) + vb(33.6M)
//            + fb(33.6M scratch, reused 3x) = 176.5 MiB

#define S_LEN 2048
#define HID 4096
#define NH 32
#define HD_C 128
#define HD 192
#define QSTRIDE (NH * HD)  // 6144

// ---------------------------------------------------------------------------
// GEMM: C[M,N] = A[M,K] * W[N,K]^T + bias[N]
// block = 256 threads, tile TM x 64, BK = 16.
// out_mode 0: row-major [M,N].  out_mode 1: scatter col n -> (n>>7)*192+(n&127),
// row stride QSTRIDE (head-interleaved q/k content slots).
// ---------------------------------------------------------------------------
template <int TM>
__global__ __launch_bounds__(256) void gemm_bt(
    const float* __restrict__ A, const float* __restrict__ W,
    const float* __restrict__ bias, float* __restrict__ C,
    int M, int N, int K, int out_mode) {
  constexpr int RPT = TM / 16;  // rows per thread (4 or 1)
  __shared__ float As[16][TM + 4];  // [k][m], +4 pad keeps float4 align, spreads banks
  __shared__ float Ws[16][68];      // [k][n]

  const int tid = threadIdx.x;
  const int tx = tid & 15, ty = tid >> 4;
  const int m0 = blockIdx.y * TM, n0 = blockIdx.x * 64;

  float acc[RPT][4];
#pragma unroll
  for (int i = 0; i < RPT; ++i)
#pragma unroll
    for (int j = 0; j < 4; ++j) acc[i][j] = 0.f;

  for (int k0 = 0; k0 < K; k0 += 16) {
    // stage A tile (TM x 16), transposed into As[k][m]
    if constexpr (TM == 64) {
      const int r = tid >> 2, c4 = (tid & 3) * 4;
      float4 av = *(const float4*)&A[(size_t)(m0 + r) * K + k0 + c4];
      As[c4 + 0][r] = av.x; As[c4 + 1][r] = av.y;
      As[c4 + 2][r] = av.z; As[c4 + 3][r] = av.w;
    } else {
      if (tid < TM * 4) {
        const int r = tid >> 2, c4 = (tid & 3) * 4;
        float4 av = *(const float4*)&A[(size_t)(m0 + r) * K + k0 + c4];
        As[c4 + 0][r] = av.x; As[c4 + 1][r] = av.y;
        As[c4 + 2][r] = av.z; As[c4 + 3][r] = av.w;
      }
    }
    // stage W tile (64 x 16), transposed into Ws[k][n]
    {
      const int r = tid >> 2, c4 = (tid & 3) * 4;
      float4 wv = *(const float4*)&W[(size_t)(n0 + r) * K + k0 + c4];
      Ws[c4 + 0][r] = wv.x; Ws[c4 + 1][r] = wv.y;
      Ws[c4 + 2][r] = wv.z; Ws[c4 + 3][r] = wv.w;
    }
    __syncthreads();

#pragma unroll
    for (int kk = 0; kk < 16; ++kk) {
      const float4 wv = *(const float4*)&Ws[kk][tx * 4];
      if constexpr (RPT == 4) {
        const float4 av = *(const float4*)&As[kk][ty * 4];
        acc[0][0] += av.x * wv.x; acc[0][1] += av.x * wv.y;
        acc[0][2] += av.x * wv.z; acc[0][3] += av.x * wv.w;
        acc[1][0] += av.y * wv.x; acc[1][1] += av.y * wv.y;
        acc[1][2] += av.y * wv.z; acc[1][3] += av.y * wv.w;
        acc[2][0] += av.z * wv.x; acc[2][1] += av.z * wv.y;
        acc[2][2] += av.z * wv.z; acc[2][3] += av.z * wv.w;
        acc[3][0] += av.w * wv.x; acc[3][1] += av.w * wv.y;
        acc[3][2] += av.w * wv.z; acc[3][3] += av.w * wv.w;
      } else {
        const float a = As[kk][ty];
        acc[0][0] += a * wv.x; acc[0][1] += a * wv.y;
        acc[0][2] += a * wv.z; acc[0][3] += a * wv.w;
      }
    }
    __syncthreads();
  }

#pragma unroll
  for (int i = 0; i < RPT; ++i) {
    const int m = m0 + ty * RPT + i;
#pragma unroll
    for (int j = 0; j < 4; ++j) {
      const int n = n0 + tx * 4 + j;
      const float val = acc[i][j] + bias[n];
      if (out_mode == 0)
        C[(size_t)m * N + n] = val;
      else
        C[(size_t)m * QSTRIDE + (n >> 7) * HD + (n & 127)] = val;
    }
  }
}

// ---------------------------------------------------------------------------
// RoPE for q: pre = [2048, 2048] (full rope projection). Pair (p, p+1024),
// cos/sin index p. Scatter into qb[s, h*192 + 128 + j], h = g>>6, j = g&63.
// f64 pow/sincos: angles reach ~2047 rad; avoid fast range-reduction error.
// ---------------------------------------------------------------------------
__global__ __launch_bounds__(256) void rope_scatter_q(
    const float* __restrict__ pre, float* __restrict__ qb) {
  const int i = blockIdx.x * blockDim.x + threadIdx.x;
  if (i >= S_LEN * 1024) return;
  const int s = i >> 10, p = i & 1023;
  const double invf = pow(10000.0, -((double)(2 * p) / 2048.0));
  double sd, cd;
  sincos((double)s * invf, &sd, &cd);
  const float c = (float)cd, sn = (float)sd;
  const float x1 = pre[(size_t)s * 2048 + p];
  const float x2 = pre[(size_t)s * 2048 + p + 1024];
  const int g1 = p, g2 = p + 1024;
  qb[(size_t)s * QSTRIDE + (g1 >> 6) * HD + 128 + (g1 & 63)] = x1 * c - x2 * sn;
  qb[(size_t)s * QSTRIDE + (g2 >> 6) * HD + 128 + (g2 & 63)] = x2 * c + x1 * sn;
}

// ---------------------------------------------------------------------------
// RoPE for k: pre = [2048, 64], rope over 64 dims, broadcast to all 32 heads.
// grid = 2048 blocks of 64 threads; thread j produces roped value j.
// ---------------------------------------------------------------------------
__global__ __launch_bounds__(64) void rope_bcast_k(
    const float* __restrict__ pre, float* __restrict__ kb) {
  const int s = blockIdx.x;
  const int j = threadIdx.x;
  const float x = pre[s * 64 + j];
  const float partner = pre[s * 64 + (j ^ 32)];
  const int p = j & 31;
  const double invf = pow(10000.0, -((double)(2 * p) / 64.0));
  double sd, cd;
  sincos((double)s * invf, &sd, &cd);
  const float val = (j < 32) ? x * (float)cd - partner * (float)sd
                             : x * (float)cd + partner * (float)sd;
  for (int h = 0; h < NH; ++h)
    kb[(size_t)s * QSTRIDE + h * HD + 128 + j] = val;
}

// ---------------------------------------------------------------------------
// RMS norm over 192-dim rows, in place. One wave per row, 3 elems/lane.
// eps = FLT_EPSILON (finfo(float32).eps in the reference).
// ---------------------------------------------------------------------------
__global__ __launch_bounds__(256) void rmsnorm_rows(float* __restrict__ X,
                                                    int nrows) {
  const int row = blockIdx.x * 4 + (threadIdx.x >> 6);
  const int lane = threadIdx.x & 63;
  if (row >= nrows) return;
  float* p = X + (size_t)row * HD;
  const float v0 = p[lane], v1 = p[lane + 64], v2 = p[lane + 128];
  float ss = v0 * v0 + v1 * v1 + v2 * v2;
#pragma unroll
  for (int off = 32; off > 0; off >>= 1) ss += __shfl_xor(ss, off, 64);
  const float r = 1.0f / sqrtf(ss * (1.0f / 192.0f) + 1.1920929e-7f);
  p[lane] = v0 * r;
  p[lane + 64] = v1 * r;
  p[lane + 128] = v2 * r;
}

// ---------------------------------------------------------------------------
// Flash attention, fp32. Q,K: [2048, 32, 192]; V,O: [2048, 4096] (h*128+d).
// BQ=16 q-rows per block, BKV=32 k-rows per step. Online softmax, mask added.
// Thread map: r = tid&15 (q row), cg = tid>>4 (8 V-cols each) -> conflict-free
// Vs reads; S-tile map sr = tid&15, sc = (tid>>4)+d*16.
// LDS: 12.5K Qs + 25K Ks + 16K Vs + 2.1K Ss = 55.7 KB -> 2 blocks/CU.
// ---------------------------------------------------------------------------
__global__ __launch_bounds__(256) void flash_attn(
    const float* __restrict__ Q, const float* __restrict__ K,
    const float* __restrict__ V, const float* __restrict__ mask,
    float* __restrict__ O) {
  constexpr int BQ = 16, BKV = 32;
  __shared__ float Qs[BQ][196];   // 192 + 4 pad (float4-aligned, bank spread)
  __shared__ float Ks[BKV][196];
  __shared__ float Vs[BKV][128];
  __shared__ float Ss[BQ][BKV + 1];

  const int h = blockIdx.y;
  const int q0 = blockIdx.x * BQ;
  const int tid = threadIdx.x;
  const float scale = 1.0f / sqrtf(192.0f);

  for (int idx = tid; idx < BQ * 48; idx += 256) {
    const int r = idx / 48, c = idx % 48;
    float4 v4 = *(const float4*)&Q[(size_t)(q0 + r) * QSTRIDE + h * HD + c * 4];
    v4.x *= scale; v4.y *= scale; v4.z *= scale; v4.w *= scale;
    *(float4*)&Qs[r][c * 4] = v4;
  }

  const int r = tid & 15;
  const int cg = tid >> 4;
  float m = -INFINITY, l = 0.f;
  float acc[8] = {0.f, 0.f, 0.f, 0.f, 0.f, 0.f, 0.f, 0.f};
  __syncthreads();

  for (int k0 = 0; k0 < S_LEN; k0 += BKV) {
    for (int idx = tid; idx < BKV * 48; idx += 256) {
      const int rr = idx / 48, c = idx % 48;
      *(float4*)&Ks[rr][c * 4] =
          *(const float4*)&K[(size_t)(k0 + rr) * QSTRIDE + h * HD + c * 4];
    }
    for (int idx = tid; idx < BKV * 32; idx += 256) {
      const int rr = idx >> 5, c = idx & 31;
      *(float4*)&Vs[rr][c * 4] =
          *(const float4*)&V[(size_t)(k0 + rr) * HID + h * HD_C + c * 4];
    }
    __syncthreads();

#pragma unroll
    for (int d = 0; d < 2; ++d) {
      const int sr = tid & 15;
      const int sc = (tid >> 4) + d * 16;
      float dot = 0.f;
#pragma unroll
      for (int k = 0; k < 192; k += 4) {
        const float4 a = *(const float4*)&Qs[sr][k];
        const float4 b = *(const float4*)&Ks[sc][k];
        dot += a.x * b.x + a.y * b.y + a.z * b.z + a.w * b.w;
      }
      Ss[sr][sc] = dot + mask[(size_t)(q0 + sr) * S_LEN + k0 + sc];
    }
    __syncthreads();

    float mt = m;
#pragma unroll
    for (int j = 0; j < BKV; ++j) mt = fmaxf(mt, Ss[r][j]);
    const float resc = __expf(m - mt);  // m=-inf first iter -> 0
    float p[BKV];
    float ls = 0.f;
#pragma unroll
    for (int j = 0; j < BKV; ++j) {
      p[j] = __expf(Ss[r][j] - mt);
      ls += p[j];
    }
    m = mt;
    l = l * resc + ls;
#pragma unroll
    for (int c = 0; c < 8; ++c) acc[c] *= resc;
#pragma unroll
    for (int j = 0; j < BKV; ++j) {
      const float pj = p[j];
      const float4 v0 = *(const float4*)&Vs[j][cg * 8];
      const float4 v1 = *(const float4*)&Vs[j][cg * 8 + 4];
      acc[0] += pj * v0.x; acc[1] += pj * v0.y;
      acc[2] += pj * v0.z; acc[3] += pj * v0.w;
      acc[4] += pj * v1.x; acc[5] += pj * v1.y;
      acc[6] += pj * v1.z; acc[7] += pj * v1.w;
    }
    __syncthreads();
  }

  const float invl = 1.0f / l;
  float* op = &O[(size_t)(q0 + r) * HID + h * HD_C + cg * 8];
#pragma unroll
  for (int c = 0; c < 8; ++c) op[c] = acc[c] * invl;
}

// ---------------------------------------------------------------------------
extern "C" void kernel_launch(void* const* d_in, const int* in_sizes, int n_in,
                              void* d_out, int out_size, void* d_ws,
                              size_t ws_size, hipStream_t stream) {
  const float* X       = (const float*)d_in[0];
  const float* mask    = (const float*)d_in[1];
  const float* Wq_lr   = (const float*)d_in[2];
  const float* bq_lr   = (const float*)d_in[3];
  const float* Wq_rope = (const float*)d_in[4];
  const float* bq_rope = (const float*)d_in[5];
  const float* Wq_c    = (const float*)d_in[6];
  const float* bq_c    = (const float*)d_in[7];
  const float* Wkv     = (const float*)d_in[8];
  const float* bkv     = (const float*)d_in[9];
  const float* Wk_rope = (const float*)d_in[10];
  const float* bk_rope = (const float*)d_in[11];
  const float* Wk_c    = (const float*)d_in[12];
  const float* bk_c    = (const float*)d_in[13];
  const float* Wv      = (const float*)d_in[14];
  const float* bv      = (const float*)d_in[15];
  const float* Wo      = (const float*)d_in[16];
  const float* bo      = (const float*)d_in[17];
  float* out = (float*)d_out;

  float* ws   = (float*)d_ws;
  float* c_q  = ws;                               // 2048*1536
  float* c_kv = c_q + (size_t)2048 * 1536;        // 2048*512
  float* qb   = c_kv + (size_t)2048 * 512;        // 2048*6144
  float* kb   = qb + (size_t)2048 * 6144;         // 2048*6144
  float* vb   = kb + (size_t)2048 * 6144;         // 2048*4096
  float* fb   = vb + (size_t)2048 * 4096;         // 2048*4096 scratch

  const dim3 blk(256);

  // 1. c_q = X @ Wq_lr^T + bq_lr
  gemm_bt<64><<<dim3(1536 / 64, 2048 / 64), blk, 0, stream>>>(
      X, Wq_lr, bq_lr, c_q, 2048, 1536, 4096, 0);
  // 2. q_content -> qb (scatter)
  gemm_bt<64><<<dim3(4096 / 64, 2048 / 64), blk, 0, stream>>>(
      c_q, Wq_c, bq_c, qb, 2048, 4096, 1536, 1);
  // 3. q_rope projection -> fb, then rope into qb
  gemm_bt<64><<<dim3(2048 / 64, 2048 / 64), blk, 0, stream>>>(
      c_q, Wq_rope, bq_rope, fb, 2048, 2048, 1536, 0);
  rope_scatter_q<<<(S_LEN * 1024) / 256, blk, 0, stream>>>(fb, qb);
  // 4. c_kv = X @ Wkv^T + bkv
  gemm_bt<64><<<dim3(512 / 64, 2048 / 64), blk, 0, stream>>>(
      X, Wkv, bkv, c_kv, 2048, 512, 4096, 0);
  // 5. k_content -> kb (scatter)
  gemm_bt<64><<<dim3(4096 / 64, 2048 / 64), blk, 0, stream>>>(
      c_kv, Wk_c, bk_c, kb, 2048, 4096, 512, 1);
  // 6. k_rope projection -> fb, then rope+broadcast into kb
  gemm_bt<16><<<dim3(1, 2048 / 16), blk, 0, stream>>>(
      X, Wk_rope, bk_rope, fb, 2048, 64, 4096, 0);
  rope_bcast_k<<<S_LEN, dim3(64), 0, stream>>>(fb, kb);
  // 7. v = c_kv @ Wv^T + bv  (layout already [s, h*128+d])
  gemm_bt<64><<<dim3(4096 / 64, 2048 / 64), blk, 0, stream>>>(
      c_kv, Wv, bv, vb, 2048, 4096, 512, 0);
  // 8. RMS norm q, k (65536 rows of 192 each)
  rmsnorm_rows<<<(S_LEN * NH) / 4, blk, 0, stream>>>(qb, S_LEN * NH);
  rmsnorm_rows<<<(S_LEN * NH) / 4, blk, 0, stream>>>(kb, S_LEN * NH);
  // 9. attention -> fb
  flash_attn<<<dim3(S_LEN / 16, NH), blk, 0, stream>>>(qb, kb, vb, mask, fb);
  // 10. out = fb @ Wo^T + bo
  gemm_bt<64><<<dim3(4096 / 64, 2048 / 64), blk, 0, stream>>>(
      fb, Wo, bo, out, 2048, 4096, 4096, 0);
}

// Round 2
// 3203.571 us; speedup vs baseline: 3.5740x; 3.5740x over previous
//
#include <hip/hip_runtime.h>
#include <hip/hip_bf16.h>
#include <math.h>

// MLA round 2: attention -> bf16 MFMA flash kernel. GEMMs remain fp32 (next
// round's lever) to isolate accuracy impact of bf16 attention.
//
// Pipeline:
//  1. c_q  = X @ Wq_lr^T + b              f32 [2048,1536]
//  2. qh  += c_q @ Wq_c^T + b             bf16 scatter [s, h*192 + 0..127]
//  3. fb   = c_q @ Wq_rope^T + b          f32 [2048,2048]; rope -> qh bf16
//  4. c_kv = X @ Wkv^T + b                f32 [2048,512]
//  5. kh  += c_kv @ Wk_c^T + b            bf16 scatter
//  6. fb   = X @ Wk_rope^T + b            f32 [2048,64]; rope+bcast -> kh bf16
//  7. vbh  = c_kv @ Wv^T + b              bf16 [2048,4096]
//  8. rmsnorm (bf16 in place, 192/row); q also scaled by 1/sqrt(192)
//  9. vt = vbh^T                          bf16 [4096,2048]
// 10. flash_attn_mfma(qh,kh,vt,mask)->fb  f32 [2048,4096]
// 11. out = fb @ Wo^T + bo                f32
//
// ws: c_q 12.6 + c_kv 4.2 + fb 33.6 + qh 25.2 + kh 25.2 + vbh 16.8 + vt 16.8
//     = 134.2 MiB (prev round proved >=176.5 available)

#define S_LEN 2048
#define HID 4096
#define NH 32
#define HD_C 128
#define HD 192
#define QSTRIDE (NH * HD)  // 6144

typedef __bf16 bf16x8 __attribute__((ext_vector_type(8)));
typedef float f32x4 __attribute__((ext_vector_type(4)));

__device__ __forceinline__ unsigned short f2bu(float x) {
  __hip_bfloat16 h = __float2bfloat16(x);
  return *reinterpret_cast<unsigned short*>(&h);
}

// ---------------------------------------------------------------------------
// GEMM: C[M,N] = A[M,K] * W[N,K]^T + bias[N]    (fp32 compute)
// out_mode 0: f32 row-major [M,N]
// out_mode 1: bf16 scatter col n -> (n>>7)*192 + (n&127), row stride 6144
// out_mode 2: bf16 row-major [M,N]
// ---------------------------------------------------------------------------
template <int TM>
__global__ __launch_bounds__(256) void gemm_bt(
    const float* __restrict__ A, const float* __restrict__ W,
    const float* __restrict__ bias, void* __restrict__ Cv,
    int M, int N, int K, int out_mode) {
  constexpr int RPT = TM / 16;
  __shared__ float As[16][TM + 4];
  __shared__ float Ws[16][68];

  const int tid = threadIdx.x;
  const int tx = tid & 15, ty = tid >> 4;
  const int m0 = blockIdx.y * TM, n0 = blockIdx.x * 64;

  float acc[RPT][4];
#pragma unroll
  for (int i = 0; i < RPT; ++i)
#pragma unroll
    for (int j = 0; j < 4; ++j) acc[i][j] = 0.f;

  for (int k0 = 0; k0 < K; k0 += 16) {
    if constexpr (TM == 64) {
      const int r = tid >> 2, c4 = (tid & 3) * 4;
      float4 av = *(const float4*)&A[(size_t)(m0 + r) * K + k0 + c4];
      As[c4 + 0][r] = av.x; As[c4 + 1][r] = av.y;
      As[c4 + 2][r] = av.z; As[c4 + 3][r] = av.w;
    } else {
      if (tid < TM * 4) {
        const int r = tid >> 2, c4 = (tid & 3) * 4;
        float4 av = *(const float4*)&A[(size_t)(m0 + r) * K + k0 + c4];
        As[c4 + 0][r] = av.x; As[c4 + 1][r] = av.y;
        As[c4 + 2][r] = av.z; As[c4 + 3][r] = av.w;
      }
    }
    {
      const int r = tid >> 2, c4 = (tid & 3) * 4;
      float4 wv = *(const float4*)&W[(size_t)(n0 + r) * K + k0 + c4];
      Ws[c4 + 0][r] = wv.x; Ws[c4 + 1][r] = wv.y;
      Ws[c4 + 2][r] = wv.z; Ws[c4 + 3][r] = wv.w;
    }
    __syncthreads();

#pragma unroll
    for (int kk = 0; kk < 16; ++kk) {
      const float4 wv = *(const float4*)&Ws[kk][tx * 4];
      if constexpr (RPT == 4) {
        const float4 av = *(const float4*)&As[kk][ty * 4];
        acc[0][0] += av.x * wv.x; acc[0][1] += av.x * wv.y;
        acc[0][2] += av.x * wv.z; acc[0][3] += av.x * wv.w;
        acc[1][0] += av.y * wv.x; acc[1][1] += av.y * wv.y;
        acc[1][2] += av.y * wv.z; acc[1][3] += av.y * wv.w;
        acc[2][0] += av.z * wv.x; acc[2][1] += av.z * wv.y;
        acc[2][2] += av.z * wv.z; acc[2][3] += av.z * wv.w;
        acc[3][0] += av.w * wv.x; acc[3][1] += av.w * wv.y;
        acc[3][2] += av.w * wv.z; acc[3][3] += av.w * wv.w;
      } else {
        const float a = As[kk][ty];
        acc[0][0] += a * wv.x; acc[0][1] += a * wv.y;
        acc[0][2] += a * wv.z; acc[0][3] += a * wv.w;
      }
    }
    __syncthreads();
  }

#pragma unroll
  for (int i = 0; i < RPT; ++i) {
    const int m = m0 + ty * RPT + i;
#pragma unroll
    for (int j = 0; j < 4; ++j) {
      const int n = n0 + tx * 4 + j;
      const float val = acc[i][j] + bias[n];
      if (out_mode == 0)
        ((float*)Cv)[(size_t)m * N + n] = val;
      else if (out_mode == 1)
        ((__hip_bfloat16*)Cv)[(size_t)m * QSTRIDE + (n >> 7) * HD + (n & 127)] =
            __float2bfloat16(val);
      else
        ((__hip_bfloat16*)Cv)[(size_t)m * N + n] = __float2bfloat16(val);
    }
  }
}

// ---------------------------------------------------------------------------
// RoPE q: pre f32 [2048,2048]; pair (p, p+1024); scatter bf16 into
// qh[s, (g>>6)*192 + 128 + (g&63)].
// ---------------------------------------------------------------------------
__global__ __launch_bounds__(256) void rope_scatter_q(
    const float* __restrict__ pre, __hip_bfloat16* __restrict__ qh) {
  const int i = blockIdx.x * blockDim.x + threadIdx.x;
  if (i >= S_LEN * 1024) return;
  const int s = i >> 10, p = i & 1023;
  const double invf = pow(10000.0, -((double)(2 * p) / 2048.0));
  double sd, cd;
  sincos((double)s * invf, &sd, &cd);
  const float c = (float)cd, sn = (float)sd;
  const float x1 = pre[(size_t)s * 2048 + p];
  const float x2 = pre[(size_t)s * 2048 + p + 1024];
  const int g1 = p, g2 = p + 1024;
  qh[(size_t)s * QSTRIDE + (g1 >> 6) * HD + 128 + (g1 & 63)] =
      __float2bfloat16(x1 * c - x2 * sn);
  qh[(size_t)s * QSTRIDE + (g2 >> 6) * HD + 128 + (g2 & 63)] =
      __float2bfloat16(x2 * c + x1 * sn);
}

// ---------------------------------------------------------------------------
// RoPE k: pre f32 [2048,64]; rope over 64, broadcast bf16 to 32 heads.
// ---------------------------------------------------------------------------
__global__ __launch_bounds__(64) void rope_bcast_k(
    const float* __restrict__ pre, __hip_bfloat16* __restrict__ kh) {
  const int s = blockIdx.x;
  const int j = threadIdx.x;
  const float x = pre[s * 64 + j];
  const float partner = pre[s * 64 + (j ^ 32)];
  const int p = j & 31;
  const double invf = pow(10000.0, -((double)(2 * p) / 64.0));
  double sd, cd;
  sincos((double)s * invf, &sd, &cd);
  const float val = (j < 32) ? x * (float)cd - partner * (float)sd
                             : x * (float)cd + partner * (float)sd;
  const __hip_bfloat16 hv = __float2bfloat16(val);
  for (int h = 0; h < NH; ++h)
    kh[(size_t)s * QSTRIDE + h * HD + 128 + j] = hv;
}

// ---------------------------------------------------------------------------
// RMS norm over 192-dim bf16 rows, in place; optional extra scale folded in.
// ---------------------------------------------------------------------------
__global__ __launch_bounds__(256) void rmsnorm_rows_bf16(
    __hip_bfloat16* __restrict__ X, int nrows, float scale) {
  const int row = blockIdx.x * 4 + (threadIdx.x >> 6);
  const int lane = threadIdx.x & 63;
  if (row >= nrows) return;
  __hip_bfloat16* p = X + (size_t)row * HD;
  const float v0 = __bfloat162float(p[lane]);
  const float v1 = __bfloat162float(p[lane + 64]);
  const float v2 = __bfloat162float(p[lane + 128]);
  float ss = v0 * v0 + v1 * v1 + v2 * v2;
#pragma unroll
  for (int off = 32; off > 0; off >>= 1) ss += __shfl_xor(ss, off, 64);
  const float r = scale / sqrtf(ss * (1.0f / 192.0f) + 1.1920929e-7f);
  p[lane] = __float2bfloat16(v0 * r);
  p[lane + 64] = __float2bfloat16(v1 * r);
  p[lane + 128] = __float2bfloat16(v2 * r);
}

// ---------------------------------------------------------------------------
// Transpose bf16 [2048,4096] -> [4096,2048], 64x64 tiles.
// ---------------------------------------------------------------------------
__global__ __launch_bounds__(256) void transpose_bf16(
    const unsigned short* __restrict__ src, unsigned short* __restrict__ dst) {
  __shared__ unsigned short T[64][72];  // [d_local][s_local]
  const int s0 = blockIdx.x * 64, d0 = blockIdx.y * 64;
  const int tid = threadIdx.x;
#pragma unroll
  for (int i = 0; i < 2; ++i) {
    const int idx = tid + i * 256;
    const int r = idx >> 3, c8 = (idx & 7) * 8;
    unsigned short tmp[8];
    *(float4*)tmp = *(const float4*)&src[(size_t)(s0 + r) * HID + d0 + c8];
#pragma unroll
    for (int j = 0; j < 8; ++j) T[c8 + j][r] = tmp[j];
  }
  __syncthreads();
#pragma unroll
  for (int i = 0; i < 2; ++i) {
    const int idx = tid + i * 256;
    const int dr = idx >> 3, sc8 = (idx & 7) * 8;
    *(float4*)&dst[(size_t)(d0 + dr) * S_LEN + s0 + sc8] =
        *(const float4*)&T[dr][sc8];
  }
}

// ---------------------------------------------------------------------------
// Flash attention, bf16 MFMA (16x16x32), fp32 softmax.
// Block: 256 thr (4 waves); BQ=16 q-rows, BKV=64 per step; one head per blockIdx.y.
// Wave w: QK^T cols [16w,16w+16); PV d-cols [32w,32w+32).
// LDS rows padded so row-stride ≡ 4 mod 32 words (balanced banks for b128).
// Fragment layouts (verified m89/m97): A/B lane l holds row/col (l&15), 8
// contiguous k at (l>>4)*8; C col=lane&15, row=(lane>>4)*4+reg.
// ---------------------------------------------------------------------------
__global__ __launch_bounds__(256) void flash_attn_mfma(
    const __hip_bfloat16* __restrict__ Qh, const __hip_bfloat16* __restrict__ Kh,
    const __hip_bfloat16* __restrict__ Vtg, const float* __restrict__ mask,
    float* __restrict__ O) {
  __shared__ __align__(16) unsigned short Qs[16][200];   // 400B stride
  __shared__ __align__(16) unsigned short Ks[64][200];
  __shared__ __align__(16) unsigned short Vs[128][72];   // [d][kv], 144B stride
  __shared__ __align__(16) float Sf[16][68];             // 272B stride
  __shared__ __align__(16) unsigned short Pb[16][72];
  __shared__ float m_row[16], l_row[16], resc_row[16];
  __shared__ float red_max[4][16], red_sum[4][16];

  const int tid = threadIdx.x;
  const int wid = tid >> 6, lane = tid & 63;
  const int cl = lane & 15, g = lane >> 4;
  const int h = blockIdx.y;
  const int q0 = blockIdx.x * 16;

  const unsigned short* Q = (const unsigned short*)Qh;
  const unsigned short* K = (const unsigned short*)Kh;
  const unsigned short* Vt = (const unsigned short*)Vtg;

  // stage Q once: 16 rows x 24 16B-chunks
  for (int idx = tid; idx < 384; idx += 256) {
    const int r = idx / 24, c = idx % 24;
    *(float4*)&Qs[r][c * 8] =
        *(const float4*)&Q[(size_t)(q0 + r) * QSTRIDE + h * HD + c * 8];
  }
  if (tid < 16) { m_row[tid] = -INFINITY; l_row[tid] = 0.f; }

  f32x4 o0 = {0.f, 0.f, 0.f, 0.f}, o1 = {0.f, 0.f, 0.f, 0.f};

  for (int k0 = 0; k0 < S_LEN; k0 += 64) {
    __syncthreads();  // prev PV reads done (and 1st-iter Q/m_row visible)
    // stage K: 64 rows x 24 chunks = 1536
#pragma unroll
    for (int i = 0; i < 6; ++i) {
      const int idx = tid + i * 256;
      const int r = idx / 24, c = idx % 24;
      *(float4*)&Ks[r][c * 8] =
          *(const float4*)&K[(size_t)(k0 + r) * QSTRIDE + h * HD + c * 8];
    }
    // stage V^T: 128 d-rows x 8 chunks = 1024
#pragma unroll
    for (int i = 0; i < 4; ++i) {
      const int idx = tid + i * 256;
      const int d = idx >> 3, jc = idx & 7;
      *(float4*)&Vs[d][jc * 8] =
          *(const float4*)&Vt[(size_t)(h * HD_C + d) * S_LEN + k0 + jc * 8];
    }
    __syncthreads();

    // ---- QK^T: wave wid computes S[:, 16w..16w+16)
    f32x4 sa = {0.f, 0.f, 0.f, 0.f};
#pragma unroll
    for (int kk = 0; kk < 6; ++kk) {
      const bf16x8 aq = *(const bf16x8*)&Qs[cl][g * 8 + kk * 32];
      const bf16x8 bk = *(const bf16x8*)&Ks[wid * 16 + cl][g * 8 + kk * 32];
      sa = __builtin_amdgcn_mfma_f32_16x16x32_bf16(aq, bk, sa, 0, 0, 0);
    }
#pragma unroll
    for (int r = 0; r < 4; ++r) {
      const int qr = g * 4 + r;
      Sf[qr][wid * 16 + cl] =
          sa[r] + mask[(size_t)(q0 + qr) * S_LEN + k0 + wid * 16 + cl];
    }
    __syncthreads();

    // ---- online softmax (block-wide; row rr, col-group cg*4..+3)
    const int rr = tid & 15, cg = tid >> 4;
    const float4 s4 = *(const float4*)&Sf[rr][cg * 4];
    float lm = fmaxf(fmaxf(s4.x, s4.y), fmaxf(s4.z, s4.w));
    lm = fmaxf(lm, __shfl_xor(lm, 16, 64));
    lm = fmaxf(lm, __shfl_xor(lm, 32, 64));
    if ((lane >> 4) == 0) red_max[wid][rr] = lm;
    __syncthreads();
    const float m_new =
        fmaxf(fmaxf(fmaxf(red_max[0][rr], red_max[1][rr]),
                    fmaxf(red_max[2][rr], red_max[3][rr])),
              m_row[rr]);
    float4 p4;
    p4.x = __expf(s4.x - m_new);
    p4.y = __expf(s4.y - m_new);
    p4.z = __expf(s4.z - m_new);
    p4.w = __expf(s4.w - m_new);
    float ls = p4.x + p4.y + p4.z + p4.w;
    ls += __shfl_xor(ls, 16, 64);
    ls += __shfl_xor(ls, 32, 64);
    if ((lane >> 4) == 0) red_sum[wid][rr] = ls;
    {
      const unsigned int lo = (unsigned int)f2bu(p4.x) | ((unsigned int)f2bu(p4.y) << 16);
      const unsigned int hi = (unsigned int)f2bu(p4.z) | ((unsigned int)f2bu(p4.w) << 16);
      uint2 pk; pk.x = lo; pk.y = hi;
      *(uint2*)&Pb[rr][cg * 4] = pk;
    }
    __syncthreads();
    if (tid < 16) {
      const float mo = m_row[tid];
      const float mn = fmaxf(fmaxf(fmaxf(red_max[0][tid], red_max[1][tid]),
                                   fmaxf(red_max[2][tid], red_max[3][tid])),
                             mo);
      const float rsc = __expf(mo - mn);
      l_row[tid] = l_row[tid] * rsc +
                   (red_sum[0][tid] + red_sum[1][tid] + red_sum[2][tid] +
                    red_sum[3][tid]);
      m_row[tid] = mn;
      resc_row[tid] = rsc;
    }
    __syncthreads();

    // ---- PV: wave wid computes O[:, 32w..32w+32)
#pragma unroll
    for (int r = 0; r < 4; ++r) {
      const float rs = resc_row[g * 4 + r];
      o0[r] *= rs;
      o1[r] *= rs;
    }
#pragma unroll
    for (int kk = 0; kk < 2; ++kk) {
      const bf16x8 ap = *(const bf16x8*)&Pb[cl][g * 8 + kk * 32];
      const bf16x8 bv0 = *(const bf16x8*)&Vs[wid * 32 + cl][g * 8 + kk * 32];
      const bf16x8 bv1 = *(const bf16x8*)&Vs[wid * 32 + 16 + cl][g * 8 + kk * 32];
      o0 = __builtin_amdgcn_mfma_f32_16x16x32_bf16(ap, bv0, o0, 0, 0, 0);
      o1 = __builtin_amdgcn_mfma_f32_16x16x32_bf16(ap, bv1, o1, 0, 0, 0);
    }
  }

#pragma unroll
  for (int r = 0; r < 4; ++r) {
    const float il = 1.0f / l_row[g * 4 + r];
    O[(size_t)(q0 + g * 4 + r) * HID + h * HD_C + wid * 32 + cl] = o0[r] * il;
    O[(size_t)(q0 + g * 4 + r) * HID + h * HD_C + wid * 32 + 16 + cl] =
        o1[r] * il;
  }
}

// ---------------------------------------------------------------------------
extern "C" void kernel_launch(void* const* d_in, const int* in_sizes, int n_in,
                              void* d_out, int out_size, void* d_ws,
                              size_t ws_size, hipStream_t stream) {
  const float* X       = (const float*)d_in[0];
  const float* mask    = (const float*)d_in[1];
  const float* Wq_lr   = (const float*)d_in[2];
  const float* bq_lr   = (const float*)d_in[3];
  const float* Wq_rope = (const float*)d_in[4];
  const float* bq_rope = (const float*)d_in[5];
  const float* Wq_c    = (const float*)d_in[6];
  const float* bq_c    = (const float*)d_in[7];
  const float* Wkv     = (const float*)d_in[8];
  const float* bkv     = (const float*)d_in[9];
  const float* Wk_rope = (const float*)d_in[10];
  const float* bk_rope = (const float*)d_in[11];
  const float* Wk_c    = (const float*)d_in[12];
  const float* bk_c    = (const float*)d_in[13];
  const float* Wv      = (const float*)d_in[14];
  const float* bv      = (const float*)d_in[15];
  const float* Wo      = (const float*)d_in[16];
  const float* bo      = (const float*)d_in[17];
  float* out = (float*)d_out;

  char* w = (char*)d_ws;
  float* c_q  = (float*)w;            w += (size_t)2048 * 1536 * 4;
  float* c_kv = (float*)w;            w += (size_t)2048 * 512 * 4;
  float* fb   = (float*)w;            w += (size_t)2048 * 4096 * 4;
  __hip_bfloat16* qh  = (__hip_bfloat16*)w;  w += (size_t)2048 * 6144 * 2;
  __hip_bfloat16* kh  = (__hip_bfloat16*)w;  w += (size_t)2048 * 6144 * 2;
  __hip_bfloat16* vbh = (__hip_bfloat16*)w;  w += (size_t)2048 * 4096 * 2;
  __hip_bfloat16* vt  = (__hip_bfloat16*)w;  w += (size_t)4096 * 2048 * 2;

  const dim3 blk(256);

  gemm_bt<64><<<dim3(24, 32), blk, 0, stream>>>(X, Wq_lr, bq_lr, c_q,
                                                2048, 1536, 4096, 0);
  gemm_bt<64><<<dim3(64, 32), blk, 0, stream>>>(c_q, Wq_c, bq_c, qh,
                                                2048, 4096, 1536, 1);
  gemm_bt<64><<<dim3(32, 32), blk, 0, stream>>>(c_q, Wq_rope, bq_rope, fb,
                                                2048, 2048, 1536, 0);
  rope_scatter_q<<<(S_LEN * 1024) / 256, blk, 0, stream>>>(fb, qh);
  gemm_bt<64><<<dim3(8, 32), blk, 0, stream>>>(X, Wkv, bkv, c_kv,
                                               2048, 512, 4096, 0);
  gemm_bt<64><<<dim3(64, 32), blk, 0, stream>>>(c_kv, Wk_c, bk_c, kh,
                                                2048, 4096, 512, 1);
  gemm_bt<16><<<dim3(1, 128), blk, 0, stream>>>(X, Wk_rope, bk_rope, fb,
                                                2048, 64, 4096, 0);
  rope_bcast_k<<<S_LEN, dim3(64), 0, stream>>>(fb, kh);
  gemm_bt<64><<<dim3(64, 32), blk, 0, stream>>>(c_kv, Wv, bv, vbh,
                                                2048, 4096, 512, 2);
  rmsnorm_rows_bf16<<<(S_LEN * NH) / 4, blk, 0, stream>>>(
      qh, S_LEN * NH, 0.07216878364870322f);  // 1/sqrt(192)
  rmsnorm_rows_bf16<<<(S_LEN * NH) / 4, blk, 0, stream>>>(kh, S_LEN * NH, 1.0f);
  transpose_bf16<<<dim3(32, 64), blk, 0, stream>>>(
      (const unsigned short*)vbh, (unsigned short*)vt);
  flash_attn_mfma<<<dim3(S_LEN / 16, NH), blk, 0, stream>>>(qh, kh, vt, mask,
                                                            fb);
  gemm_bt<64><<<dim3(64, 32), blk, 0, stream>>>(fb, Wo, bo, out,
                                                2048, 4096, 4096, 0);
}

// Round 3
// 1437.655 us; speedup vs baseline: 7.9642x; 2.2283x over previous
//
#include <hip/hip_runtime.h>
#include <hip/hip_bf16.h>
#include <math.h>

// MLA round 3: all large GEMMs -> bf16 MFMA (m97-structure: 128x128 tile,
// 4 waves, BK=32, global_load_lds staging). fp32 weights converted to bf16
// into a reused scratch (wbuf) right before each GEMM. V^T computed directly
// as Wv @ c_kv^T (no transpose kernel). Flash attention unchanged except
// bf16 output feeding the Wo GEMM.
//
// ws layout (MB): Xb 16.8 | wbuf 33.6 | c_qb 6.3 | c_kvb 2.1 | fb 16.8 (f32,
// reused: q_rope pre -> k_rope pre -> ob bf16) | qh 25.2 | kh 25.2 | vt 16.8
// = 162.8 MB

#define S_LEN 2048
#define HID 4096
#define NH 32
#define HD_C 128
#define HD 192
#define QSTRIDE (NH * HD)  // 6144

typedef __bf16 bf16x8 __attribute__((ext_vector_type(8)));
typedef float f32x4 __attribute__((ext_vector_type(4)));

__device__ __forceinline__ unsigned short f2bu(float x) {
  __hip_bfloat16 h = __float2bfloat16(x);
  return *reinterpret_cast<unsigned short*>(&h);
}

// ---------------------------------------------------------------------------
// f32 -> bf16 elementwise convert, 8 elems/thread-iter (16B ld x2, 16B st).
// ---------------------------------------------------------------------------
__global__ __launch_bounds__(256) void f32_to_bf16_vec(
    const float* __restrict__ src, unsigned short* __restrict__ dst, int n8) {
  for (int i = blockIdx.x * 256 + threadIdx.x; i < n8; i += gridDim.x * 256) {
    const float4 a = ((const float4*)src)[(size_t)i * 2];
    const float4 b = ((const float4*)src)[(size_t)i * 2 + 1];
    unsigned short u[8] = {f2bu(a.x), f2bu(a.y), f2bu(a.z), f2bu(a.w),
                           f2bu(b.x), f2bu(b.y), f2bu(b.z), f2bu(b.w)};
    *(float4*)&dst[(size_t)i * 8] = *(float4*)u;
  }
}

// ---------------------------------------------------------------------------
// bf16 MFMA GEMM: C[M,N] = A[M,K](bf16) @ W[N,K](bf16)^T + bias
// 128x128 tile, 256 thr (4 waves 2x2), BK=32, 16x16x32 MFMA, m97 structure.
// M,N % 128 == 0; K % 32 == 0.
// out_mode: 0 = f32 [M,N]; 1 = bf16 scatter col n -> (n>>7)*192+(n&127),
//           row stride 6144; 2 = bf16 [M,N].
// bias_mode: 0 = bias[col], 1 = bias[row].
// ---------------------------------------------------------------------------
__global__ __launch_bounds__(256) void gemm_bf16(
    const unsigned short* __restrict__ A, const unsigned short* __restrict__ W,
    const float* __restrict__ bias, void* __restrict__ Cv,
    int M, int N, int K, int out_mode, int bias_mode) {
  __shared__ __align__(16) unsigned short As[128 * 32];
  __shared__ __align__(16) unsigned short Bs[128 * 32];

  const int tid = threadIdx.x;
  const int wid = tid >> 6, lane = tid & 63;
  const int cl = lane & 15, g = lane >> 4;
  const int wr = wid >> 1, wc = wid & 1;
  const int m0 = blockIdx.y * 128, n0 = blockIdx.x * 128;

  f32x4 acc[4][4] = {};

  for (int k0 = 0; k0 < K; k0 += 32) {
    __syncthreads();  // all waves done reading LDS from previous step
    // stage A,B tiles: each 8KB = 512 x 16B chunks; chunk c -> row c>>2,
    // k-elems (c&3)*8. Wave w, round j covers chunks [j*256+w*64, +64).
#pragma unroll
    for (int j = 0; j < 2; ++j) {
      const int c = j * 256 + wid * 64 + lane;
      const unsigned short* ga =
          &A[(size_t)(m0 + (c >> 2)) * K + k0 + (c & 3) * 8];
      __builtin_amdgcn_global_load_lds(
          (const __attribute__((address_space(1))) unsigned int*)ga,
          (__attribute__((address_space(3))) unsigned int*)&As[(size_t)(j * 256 + wid * 64) * 8],
          16, 0, 0);
      const unsigned short* gb =
          &W[(size_t)(n0 + (c >> 2)) * K + k0 + (c & 3) * 8];
      __builtin_amdgcn_global_load_lds(
          (const __attribute__((address_space(1))) unsigned int*)gb,
          (__attribute__((address_space(3))) unsigned int*)&Bs[(size_t)(j * 256 + wid * 64) * 8],
          16, 0, 0);
    }
    __syncthreads();  // vmcnt(0) drain: staged tiles visible

    bf16x8 a[4], b[4];
#pragma unroll
    for (int m = 0; m < 4; ++m)
      a[m] = *(const bf16x8*)&As[(size_t)(wr * 64 + m * 16 + cl) * 32 + g * 8];
#pragma unroll
    for (int n = 0; n < 4; ++n)
      b[n] = *(const bf16x8*)&Bs[(size_t)(wc * 64 + n * 16 + cl) * 32 + g * 8];
#pragma unroll
    for (int m = 0; m < 4; ++m)
#pragma unroll
      for (int n = 0; n < 4; ++n)
        acc[m][n] =
            __builtin_amdgcn_mfma_f32_16x16x32_bf16(a[m], b[n], acc[m][n], 0, 0, 0);
  }

  // epilogue: C row = m-index (A), col = lane&15-index (B); row=(g*4+r)
#pragma unroll
  for (int m = 0; m < 4; ++m) {
    const int row = m0 + wr * 64 + m * 16 + g * 4;
#pragma unroll
    for (int n = 0; n < 4; ++n) {
      const int col = n0 + wc * 64 + n * 16 + cl;
#pragma unroll
      for (int r = 0; r < 4; ++r) {
        const float val =
            acc[m][n][r] + (bias_mode ? bias[row + r] : bias[col]);
        if (out_mode == 0)
          ((float*)Cv)[(size_t)(row + r) * N + col] = val;
        else if (out_mode == 1)
          ((__hip_bfloat16*)Cv)[(size_t)(row + r) * QSTRIDE + (col >> 7) * HD +
                                (col & 127)] = __float2bfloat16(val);
        else
          ((__hip_bfloat16*)Cv)[(size_t)(row + r) * N + col] =
              __float2bfloat16(val);
      }
    }
  }
}

// ---------------------------------------------------------------------------
// fp32 GEMM (kept for the tiny k_rope projection, N=64).
// ---------------------------------------------------------------------------
template <int TM>
__global__ __launch_bounds__(256) void gemm_bt(
    const float* __restrict__ A, const float* __restrict__ W,
    const float* __restrict__ bias, void* __restrict__ Cv,
    int M, int N, int K, int out_mode) {
  constexpr int RPT = TM / 16;
  __shared__ float As[16][TM + 4];
  __shared__ float Ws[16][68];

  const int tid = threadIdx.x;
  const int tx = tid & 15, ty = tid >> 4;
  const int m0 = blockIdx.y * TM, n0 = blockIdx.x * 64;

  float acc[RPT][4];
#pragma unroll
  for (int i = 0; i < RPT; ++i)
#pragma unroll
    for (int j = 0; j < 4; ++j) acc[i][j] = 0.f;

  for (int k0 = 0; k0 < K; k0 += 16) {
    if (tid < TM * 4) {
      const int r = tid >> 2, c4 = (tid & 3) * 4;
      float4 av = *(const float4*)&A[(size_t)(m0 + r) * K + k0 + c4];
      As[c4 + 0][r] = av.x; As[c4 + 1][r] = av.y;
      As[c4 + 2][r] = av.z; As[c4 + 3][r] = av.w;
    }
    {
      const int r = tid >> 2, c4 = (tid & 3) * 4;
      float4 wv = *(const float4*)&W[(size_t)(n0 + r) * K + k0 + c4];
      Ws[c4 + 0][r] = wv.x; Ws[c4 + 1][r] = wv.y;
      Ws[c4 + 2][r] = wv.z; Ws[c4 + 3][r] = wv.w;
    }
    __syncthreads();
#pragma unroll
    for (int kk = 0; kk < 16; ++kk) {
      const float4 wv = *(const float4*)&Ws[kk][tx * 4];
      const float a = As[kk][ty];
      acc[0][0] += a * wv.x; acc[0][1] += a * wv.y;
      acc[0][2] += a * wv.z; acc[0][3] += a * wv.w;
    }
    __syncthreads();
  }

#pragma unroll
  for (int i = 0; i < RPT; ++i) {
    const int m = m0 + ty * RPT + i;
#pragma unroll
    for (int j = 0; j < 4; ++j) {
      const int n = n0 + tx * 4 + j;
      ((float*)Cv)[(size_t)m * N + n] = acc[i][j] + bias[n];
    }
  }
}

// ---------------------------------------------------------------------------
// RoPE q: pre f32 [2048,2048]; pair (p, p+1024); scatter bf16 into
// qh[s, (g>>6)*192 + 128 + (g&63)].
// ---------------------------------------------------------------------------
__global__ __launch_bounds__(256) void rope_scatter_q(
    const float* __restrict__ pre, __hip_bfloat16* __restrict__ qh) {
  const int i = blockIdx.x * blockDim.x + threadIdx.x;
  if (i >= S_LEN * 1024) return;
  const int s = i >> 10, p = i & 1023;
  const double invf = pow(10000.0, -((double)(2 * p) / 2048.0));
  double sd, cd;
  sincos((double)s * invf, &sd, &cd);
  const float c = (float)cd, sn = (float)sd;
  const float x1 = pre[(size_t)s * 2048 + p];
  const float x2 = pre[(size_t)s * 2048 + p + 1024];
  const int g1 = p, g2 = p + 1024;
  qh[(size_t)s * QSTRIDE + (g1 >> 6) * HD + 128 + (g1 & 63)] =
      __float2bfloat16(x1 * c - x2 * sn);
  qh[(size_t)s * QSTRIDE + (g2 >> 6) * HD + 128 + (g2 & 63)] =
      __float2bfloat16(x2 * c + x1 * sn);
}

// ---------------------------------------------------------------------------
// RoPE k: pre f32 [2048,64]; rope over 64, broadcast bf16 to 32 heads.
// ---------------------------------------------------------------------------
__global__ __launch_bounds__(64) void rope_bcast_k(
    const float* __restrict__ pre, __hip_bfloat16* __restrict__ kh) {
  const int s = blockIdx.x;
  const int j = threadIdx.x;
  const float x = pre[s * 64 + j];
  const float partner = pre[s * 64 + (j ^ 32)];
  const int p = j & 31;
  const double invf = pow(10000.0, -((double)(2 * p) / 64.0));
  double sd, cd;
  sincos((double)s * invf, &sd, &cd);
  const float val = (j < 32) ? x * (float)cd - partner * (float)sd
                             : x * (float)cd + partner * (float)sd;
  const __hip_bfloat16 hv = __float2bfloat16(val);
  for (int h = 0; h < NH; ++h)
    kh[(size_t)s * QSTRIDE + h * HD + 128 + j] = hv;
}

// ---------------------------------------------------------------------------
// RMS norm over 192-dim bf16 rows, in place; optional extra scale folded in.
// ---------------------------------------------------------------------------
__global__ __launch_bounds__(256) void rmsnorm_rows_bf16(
    __hip_bfloat16* __restrict__ X, int nrows, float scale) {
  const int row = blockIdx.x * 4 + (threadIdx.x >> 6);
  const int lane = threadIdx.x & 63;
  if (row >= nrows) return;
  __hip_bfloat16* p = X + (size_t)row * HD;
  const float v0 = __bfloat162float(p[lane]);
  const float v1 = __bfloat162float(p[lane + 64]);
  const float v2 = __bfloat162float(p[lane + 128]);
  float ss = v0 * v0 + v1 * v1 + v2 * v2;
#pragma unroll
  for (int off = 32; off > 0; off >>= 1) ss += __shfl_xor(ss, off, 64);
  const float r = scale / sqrtf(ss * (1.0f / 192.0f) + 1.1920929e-7f);
  p[lane] = __float2bfloat16(v0 * r);
  p[lane + 64] = __float2bfloat16(v1 * r);
  p[lane + 128] = __float2bfloat16(v2 * r);
}

// ---------------------------------------------------------------------------
// Flash attention, bf16 MFMA (16x16x32), fp32 softmax, bf16 output.
// Block: 256 thr (4 waves); BQ=16 q-rows, BKV=64 per step; head = blockIdx.y.
// ---------------------------------------------------------------------------
__global__ __launch_bounds__(256) void flash_attn_mfma(
    const __hip_bfloat16* __restrict__ Qh, const __hip_bfloat16* __restrict__ Kh,
    const __hip_bfloat16* __restrict__ Vtg, const float* __restrict__ mask,
    __hip_bfloat16* __restrict__ O) {
  __shared__ __align__(16) unsigned short Qs[16][200];
  __shared__ __align__(16) unsigned short Ks[64][200];
  __shared__ __align__(16) unsigned short Vs[128][72];
  __shared__ __align__(16) float Sf[16][68];
  __shared__ __align__(16) unsigned short Pb[16][72];
  __shared__ float m_row[16], l_row[16], resc_row[16];
  __shared__ float red_max[4][16], red_sum[4][16];

  const int tid = threadIdx.x;
  const int wid = tid >> 6, lane = tid & 63;
  const int cl = lane & 15, g = lane >> 4;
  const int h = blockIdx.y;
  const int q0 = blockIdx.x * 16;

  const unsigned short* Q = (const unsigned short*)Qh;
  const unsigned short* K = (const unsigned short*)Kh;
  const unsigned short* Vt = (const unsigned short*)Vtg;

  for (int idx = tid; idx < 384; idx += 256) {
    const int r = idx / 24, c = idx % 24;
    *(float4*)&Qs[r][c * 8] =
        *(const float4*)&Q[(size_t)(q0 + r) * QSTRIDE + h * HD + c * 8];
  }
  if (tid < 16) { m_row[tid] = -INFINITY; l_row[tid] = 0.f; }

  f32x4 o0 = {0.f, 0.f, 0.f, 0.f}, o1 = {0.f, 0.f, 0.f, 0.f};

  for (int k0 = 0; k0 < S_LEN; k0 += 64) {
    __syncthreads();
#pragma unroll
    for (int i = 0; i < 6; ++i) {
      const int idx = tid + i * 256;
      const int r = idx / 24, c = idx % 24;
      *(float4*)&Ks[r][c * 8] =
          *(const float4*)&K[(size_t)(k0 + r) * QSTRIDE + h * HD + c * 8];
    }
#pragma unroll
    for (int i = 0; i < 4; ++i) {
      const int idx = tid + i * 256;
      const int d = idx >> 3, jc = idx & 7;
      *(float4*)&Vs[d][jc * 8] =
          *(const float4*)&Vt[(size_t)(h * HD_C + d) * S_LEN + k0 + jc * 8];
    }
    __syncthreads();

    f32x4 sa = {0.f, 0.f, 0.f, 0.f};
#pragma unroll
    for (int kk = 0; kk < 6; ++kk) {
      const bf16x8 aq = *(const bf16x8*)&Qs[cl][g * 8 + kk * 32];
      const bf16x8 bk = *(const bf16x8*)&Ks[wid * 16 + cl][g * 8 + kk * 32];
      sa = __builtin_amdgcn_mfma_f32_16x16x32_bf16(aq, bk, sa, 0, 0, 0);
    }
#pragma unroll
    for (int r = 0; r < 4; ++r) {
      const int qr = g * 4 + r;
      Sf[qr][wid * 16 + cl] =
          sa[r] + mask[(size_t)(q0 + qr) * S_LEN + k0 + wid * 16 + cl];
    }
    __syncthreads();

    const int rr = tid & 15, cg = tid >> 4;
    const float4 s4 = *(const float4*)&Sf[rr][cg * 4];
    float lm = fmaxf(fmaxf(s4.x, s4.y), fmaxf(s4.z, s4.w));
    lm = fmaxf(lm, __shfl_xor(lm, 16, 64));
    lm = fmaxf(lm, __shfl_xor(lm, 32, 64));
    if ((lane >> 4) == 0) red_max[wid][rr] = lm;
    __syncthreads();
    const float m_new =
        fmaxf(fmaxf(fmaxf(red_max[0][rr], red_max[1][rr]),
                    fmaxf(red_max[2][rr], red_max[3][rr])),
              m_row[rr]);
    float4 p4;
    p4.x = __expf(s4.x - m_new);
    p4.y = __expf(s4.y - m_new);
    p4.z = __expf(s4.z - m_new);
    p4.w = __expf(s4.w - m_new);
    float ls = p4.x + p4.y + p4.z + p4.w;
    ls += __shfl_xor(ls, 16, 64);
    ls += __shfl_xor(ls, 32, 64);
    if ((lane >> 4) == 0) red_sum[wid][rr] = ls;
    {
      const unsigned int lo = (unsigned int)f2bu(p4.x) | ((unsigned int)f2bu(p4.y) << 16);
      const unsigned int hi = (unsigned int)f2bu(p4.z) | ((unsigned int)f2bu(p4.w) << 16);
      uint2 pk; pk.x = lo; pk.y = hi;
      *(uint2*)&Pb[rr][cg * 4] = pk;
    }
    __syncthreads();
    if (tid < 16) {
      const float mo = m_row[tid];
      const float mn = fmaxf(fmaxf(fmaxf(red_max[0][tid], red_max[1][tid]),
                                   fmaxf(red_max[2][tid], red_max[3][tid])),
                             mo);
      const float rsc = __expf(mo - mn);
      l_row[tid] = l_row[tid] * rsc +
                   (red_sum[0][tid] + red_sum[1][tid] + red_sum[2][tid] +
                    red_sum[3][tid]);
      m_row[tid] = mn;
      resc_row[tid] = rsc;
    }
    __syncthreads();

#pragma unroll
    for (int r = 0; r < 4; ++r) {
      const float rs = resc_row[g * 4 + r];
      o0[r] *= rs;
      o1[r] *= rs;
    }
#pragma unroll
    for (int kk = 0; kk < 2; ++kk) {
      const bf16x8 ap = *(const bf16x8*)&Pb[cl][g * 8 + kk * 32];
      const bf16x8 bv0 = *(const bf16x8*)&Vs[wid * 32 + cl][g * 8 + kk * 32];
      const bf16x8 bv1 = *(const bf16x8*)&Vs[wid * 32 + 16 + cl][g * 8 + kk * 32];
      o0 = __builtin_amdgcn_mfma_f32_16x16x32_bf16(ap, bv0, o0, 0, 0, 0);
      o1 = __builtin_amdgcn_mfma_f32_16x16x32_bf16(ap, bv1, o1, 0, 0, 0);
    }
  }

#pragma unroll
  for (int r = 0; r < 4; ++r) {
    const float il = 1.0f / l_row[g * 4 + r];
    O[(size_t)(q0 + g * 4 + r) * HID + h * HD_C + wid * 32 + cl] =
        __float2bfloat16(o0[r] * il);
    O[(size_t)(q0 + g * 4 + r) * HID + h * HD_C + wid * 32 + 16 + cl] =
        __float2bfloat16(o1[r] * il);
  }
}

// ---------------------------------------------------------------------------
extern "C" void kernel_launch(void* const* d_in, const int* in_sizes, int n_in,
                              void* d_out, int out_size, void* d_ws,
                              size_t ws_size, hipStream_t stream) {
  const float* X       = (const float*)d_in[0];
  const float* mask    = (const float*)d_in[1];
  const float* Wq_lr   = (const float*)d_in[2];
  const float* bq_lr   = (const float*)d_in[3];
  const float* Wq_rope = (const float*)d_in[4];
  const float* bq_rope = (const float*)d_in[5];
  const float* Wq_c    = (const float*)d_in[6];
  const float* bq_c    = (const float*)d_in[7];
  const float* Wkv     = (const float*)d_in[8];
  const float* bkv     = (const float*)d_in[9];
  const float* Wk_rope = (const float*)d_in[10];
  const float* bk_rope = (const float*)d_in[11];
  const float* Wk_c    = (const float*)d_in[12];
  const float* bk_c    = (const float*)d_in[13];
  const float* Wv      = (const float*)d_in[14];
  const float* bv      = (const float*)d_in[15];
  const float* Wo      = (const float*)d_in[16];
  const float* bo      = (const float*)d_in[17];
  float* out = (float*)d_out;

  char* w = (char*)d_ws;
  unsigned short* Xb   = (unsigned short*)w;  w += (size_t)2048 * 4096 * 2;
  unsigned short* wbuf = (unsigned short*)w;  w += (size_t)4096 * 4096 * 2;
  unsigned short* c_qb = (unsigned short*)w;  w += (size_t)2048 * 1536 * 2;
  unsigned short* c_kvb= (unsigned short*)w;  w += (size_t)2048 * 512 * 2;
  float* fb            = (float*)w;           w += (size_t)2048 * 2048 * 4;
  __hip_bfloat16* qh   = (__hip_bfloat16*)w;  w += (size_t)2048 * 6144 * 2;
  __hip_bfloat16* kh   = (__hip_bfloat16*)w;  w += (size_t)2048 * 6144 * 2;
  __hip_bfloat16* vt   = (__hip_bfloat16*)w;  w += (size_t)4096 * 2048 * 2;
  __hip_bfloat16* ob   = (__hip_bfloat16*)fb;  // reuse fb (16.8MB, bf16 16.8MB)

  const dim3 blk(256);
  auto cvt = [&](const float* s, unsigned short* d, int n) {
    const int n8 = n / 8;
    const int nb = min(2048, (n8 + 255) / 256);
    f32_to_bf16_vec<<<nb, blk, 0, stream>>>(s, d, n8);
  };

  // X -> bf16
  cvt(X, Xb, 2048 * 4096);
  // 1. c_q = X @ Wq_lr^T      [2048,1536] bf16
  cvt(Wq_lr, wbuf, 1536 * 4096);
  gemm_bf16<<<dim3(12, 16), blk, 0, stream>>>(Xb, wbuf, bq_lr, c_qb,
                                              2048, 1536, 4096, 2, 0);
  // 2. q_content -> qh (scatter)
  cvt(Wq_c, wbuf, 4096 * 1536);
  gemm_bf16<<<dim3(32, 16), blk, 0, stream>>>(c_qb, wbuf, bq_c, qh,
                                              2048, 4096, 1536, 1, 0);
  // 3. q_rope pre -> fb (f32), rope -> qh
  cvt(Wq_rope, wbuf, 2048 * 1536);
  gemm_bf16<<<dim3(16, 16), blk, 0, stream>>>(c_qb, wbuf, bq_rope, fb,
                                              2048, 2048, 1536, 0, 0);
  rope_scatter_q<<<(S_LEN * 1024) / 256, blk, 0, stream>>>(fb, qh);
  // 4. c_kv
  cvt(Wkv, wbuf, 512 * 4096);
  gemm_bf16<<<dim3(4, 16), blk, 0, stream>>>(Xb, wbuf, bkv, c_kvb,
                                             2048, 512, 4096, 2, 0);
  // 5. k_content -> kh (scatter)
  cvt(Wk_c, wbuf, 4096 * 512);
  gemm_bf16<<<dim3(32, 16), blk, 0, stream>>>(c_kvb, wbuf, bk_c, kh,
                                              2048, 4096, 512, 1, 0);
  // 6. k_rope pre (f32, tiny) -> fb, rope+bcast -> kh
  gemm_bt<16><<<dim3(1, 128), blk, 0, stream>>>(X, Wk_rope, bk_rope, fb,
                                                2048, 64, 4096, 0);
  rope_bcast_k<<<S_LEN, dim3(64), 0, stream>>>(fb, kh);
  // 7. vt[d,s] = Wv @ c_kv^T + bv[d]  (direct transposed V)
  cvt(Wv, wbuf, 4096 * 512);
  gemm_bf16<<<dim3(16, 32), blk, 0, stream>>>(wbuf, c_kvb, bv, vt,
                                              4096, 2048, 512, 2, 1);
  // 8. RMS norm q (x 1/sqrt(192)), k
  rmsnorm_rows_bf16<<<(S_LEN * NH) / 4, blk, 0, stream>>>(
      qh, S_LEN * NH, 0.07216878364870322f);
  rmsnorm_rows_bf16<<<(S_LEN * NH) / 4, blk, 0, stream>>>(kh, S_LEN * NH, 1.0f);
  // 9. attention -> ob (bf16, overlays fb)
  flash_attn_mfma<<<dim3(S_LEN / 16, NH), blk, 0, stream>>>(qh, kh, vt, mask,
                                                            ob);
  // 10. out = ob @ Wo^T + bo (f32)
  cvt(Wo, wbuf, 4096 * 4096);
  gemm_bf16<<<dim3(32, 16), blk, 0, stream>>>((const unsigned short*)ob, wbuf,
                                              bo, out, 2048, 4096, 4096, 0, 0);
}

// Round 4
// 1061.537 us; speedup vs baseline: 10.7860x; 1.3543x over previous
//
#include <hip/hip_runtime.h>
#include <hip/hip_bf16.h>
#include <math.h>

// MLA round 4: flash attention rebuilt with swapped-operand MFMA structure.
// BQ=128 (4 waves x 32 q-rows), KVBLK=64. S^T = mfma(K, Q_regs) puts a full
// q-row per lane (q = lane&15) -> wave-local softmax, uniform per-lane
// rescale; O^T = mfma(V^T, P) keeps that orientation. P via per-wave LDS
// [q][kv]. 2 barriers/step, 80 MFMA/wave/step. Rest of pipeline unchanged.

#define S_LEN 2048
#define HID 4096
#define NH 32
#define HD_C 128
#define HD 192
#define QSTRIDE (NH * HD)  // 6144

typedef __bf16 bf16x8 __attribute__((ext_vector_type(8)));
typedef float f32x4 __attribute__((ext_vector_type(4)));

__device__ __forceinline__ unsigned short f2bu(float x) {
  __hip_bfloat16 h = __float2bfloat16(x);
  return *reinterpret_cast<unsigned short*>(&h);
}

// ---------------------------------------------------------------------------
// f32 -> bf16 elementwise convert.
// ---------------------------------------------------------------------------
__global__ __launch_bounds__(256) void f32_to_bf16_vec(
    const float* __restrict__ src, unsigned short* __restrict__ dst, int n8) {
  for (int i = blockIdx.x * 256 + threadIdx.x; i < n8; i += gridDim.x * 256) {
    const float4 a = ((const float4*)src)[(size_t)i * 2];
    const float4 b = ((const float4*)src)[(size_t)i * 2 + 1];
    unsigned short u[8] = {f2bu(a.x), f2bu(a.y), f2bu(a.z), f2bu(a.w),
                           f2bu(b.x), f2bu(b.y), f2bu(b.z), f2bu(b.w)};
    *(float4*)&dst[(size_t)i * 8] = *(float4*)u;
  }
}

// ---------------------------------------------------------------------------
// bf16 MFMA GEMM (m97 structure, 128x128 tile, BK=32). Unchanged from r3.
// ---------------------------------------------------------------------------
__global__ __launch_bounds__(256) void gemm_bf16(
    const unsigned short* __restrict__ A, const unsigned short* __restrict__ W,
    const float* __restrict__ bias, void* __restrict__ Cv,
    int M, int N, int K, int out_mode, int bias_mode) {
  __shared__ __align__(16) unsigned short As[128 * 32];
  __shared__ __align__(16) unsigned short Bs[128 * 32];

  const int tid = threadIdx.x;
  const int wid = tid >> 6, lane = tid & 63;
  const int cl = lane & 15, g = lane >> 4;
  const int wr = wid >> 1, wc = wid & 1;
  const int m0 = blockIdx.y * 128, n0 = blockIdx.x * 128;

  f32x4 acc[4][4] = {};

  for (int k0 = 0; k0 < K; k0 += 32) {
    __syncthreads();
#pragma unroll
    for (int j = 0; j < 2; ++j) {
      const int c = j * 256 + wid * 64 + lane;
      const unsigned short* ga =
          &A[(size_t)(m0 + (c >> 2)) * K + k0 + (c & 3) * 8];
      __builtin_amdgcn_global_load_lds(
          (const __attribute__((address_space(1))) unsigned int*)ga,
          (__attribute__((address_space(3))) unsigned int*)&As[(size_t)(j * 256 + wid * 64) * 8],
          16, 0, 0);
      const unsigned short* gb =
          &W[(size_t)(n0 + (c >> 2)) * K + k0 + (c & 3) * 8];
      __builtin_amdgcn_global_load_lds(
          (const __attribute__((address_space(1))) unsigned int*)gb,
          (__attribute__((address_space(3))) unsigned int*)&Bs[(size_t)(j * 256 + wid * 64) * 8],
          16, 0, 0);
    }
    __syncthreads();

    bf16x8 a[4], b[4];
#pragma unroll
    for (int m = 0; m < 4; ++m)
      a[m] = *(const bf16x8*)&As[(size_t)(wr * 64 + m * 16 + cl) * 32 + g * 8];
#pragma unroll
    for (int n = 0; n < 4; ++n)
      b[n] = *(const bf16x8*)&Bs[(size_t)(wc * 64 + n * 16 + cl) * 32 + g * 8];
#pragma unroll
    for (int m = 0; m < 4; ++m)
#pragma unroll
      for (int n = 0; n < 4; ++n)
        acc[m][n] =
            __builtin_amdgcn_mfma_f32_16x16x32_bf16(a[m], b[n], acc[m][n], 0, 0, 0);
  }

#pragma unroll
  for (int m = 0; m < 4; ++m) {
    const int row = m0 + wr * 64 + m * 16 + g * 4;
#pragma unroll
    for (int n = 0; n < 4; ++n) {
      const int col = n0 + wc * 64 + n * 16 + cl;
#pragma unroll
      for (int r = 0; r < 4; ++r) {
        const float val =
            acc[m][n][r] + (bias_mode ? bias[row + r] : bias[col]);
        if (out_mode == 0)
          ((float*)Cv)[(size_t)(row + r) * N + col] = val;
        else if (out_mode == 1)
          ((__hip_bfloat16*)Cv)[(size_t)(row + r) * QSTRIDE + (col >> 7) * HD +
                                (col & 127)] = __float2bfloat16(val);
        else
          ((__hip_bfloat16*)Cv)[(size_t)(row + r) * N + col] =
              __float2bfloat16(val);
      }
    }
  }
}

// ---------------------------------------------------------------------------
// fp32 GEMM (tiny k_rope projection, N=64).
// ---------------------------------------------------------------------------
template <int TM>
__global__ __launch_bounds__(256) void gemm_bt(
    const float* __restrict__ A, const float* __restrict__ W,
    const float* __restrict__ bias, void* __restrict__ Cv,
    int M, int N, int K, int out_mode) {
  constexpr int RPT = TM / 16;
  __shared__ float As[16][TM + 4];
  __shared__ float Ws[16][68];

  const int tid = threadIdx.x;
  const int tx = tid & 15, ty = tid >> 4;
  const int m0 = blockIdx.y * TM, n0 = blockIdx.x * 64;

  float acc[RPT][4];
#pragma unroll
  for (int i = 0; i < RPT; ++i)
#pragma unroll
    for (int j = 0; j < 4; ++j) acc[i][j] = 0.f;

  for (int k0 = 0; k0 < K; k0 += 16) {
    if (tid < TM * 4) {
      const int r = tid >> 2, c4 = (tid & 3) * 4;
      float4 av = *(const float4*)&A[(size_t)(m0 + r) * K + k0 + c4];
      As[c4 + 0][r] = av.x; As[c4 + 1][r] = av.y;
      As[c4 + 2][r] = av.z; As[c4 + 3][r] = av.w;
    }
    {
      const int r = tid >> 2, c4 = (tid & 3) * 4;
      float4 wv = *(const float4*)&W[(size_t)(n0 + r) * K + k0 + c4];
      Ws[c4 + 0][r] = wv.x; Ws[c4 + 1][r] = wv.y;
      Ws[c4 + 2][r] = wv.z; Ws[c4 + 3][r] = wv.w;
    }
    __syncthreads();
#pragma unroll
    for (int kk = 0; kk < 16; ++kk) {
      const float4 wv = *(const float4*)&Ws[kk][tx * 4];
      const float a = As[kk][ty];
      acc[0][0] += a * wv.x; acc[0][1] += a * wv.y;
      acc[0][2] += a * wv.z; acc[0][3] += a * wv.w;
    }
    __syncthreads();
  }

#pragma unroll
  for (int i = 0; i < RPT; ++i) {
    const int m = m0 + ty * RPT + i;
#pragma unroll
    for (int j = 0; j < 4; ++j) {
      const int n = n0 + tx * 4 + j;
      ((float*)Cv)[(size_t)m * N + n] = acc[i][j] + bias[n];
    }
  }
}

// ---------------------------------------------------------------------------
// RoPE q scatter (unchanged).
// ---------------------------------------------------------------------------
__global__ __launch_bounds__(256) void rope_scatter_q(
    const float* __restrict__ pre, __hip_bfloat16* __restrict__ qh) {
  const int i = blockIdx.x * blockDim.x + threadIdx.x;
  if (i >= S_LEN * 1024) return;
  const int s = i >> 10, p = i & 1023;
  const double invf = pow(10000.0, -((double)(2 * p) / 2048.0));
  double sd, cd;
  sincos((double)s * invf, &sd, &cd);
  const float c = (float)cd, sn = (float)sd;
  const float x1 = pre[(size_t)s * 2048 + p];
  const float x2 = pre[(size_t)s * 2048 + p + 1024];
  const int g1 = p, g2 = p + 1024;
  qh[(size_t)s * QSTRIDE + (g1 >> 6) * HD + 128 + (g1 & 63)] =
      __float2bfloat16(x1 * c - x2 * sn);
  qh[(size_t)s * QSTRIDE + (g2 >> 6) * HD + 128 + (g2 & 63)] =
      __float2bfloat16(x2 * c + x1 * sn);
}

// ---------------------------------------------------------------------------
// RoPE k broadcast (unchanged).
// ---------------------------------------------------------------------------
__global__ __launch_bounds__(64) void rope_bcast_k(
    const float* __restrict__ pre, __hip_bfloat16* __restrict__ kh) {
  const int s = blockIdx.x;
  const int j = threadIdx.x;
  const float x = pre[s * 64 + j];
  const float partner = pre[s * 64 + (j ^ 32)];
  const int p = j & 31;
  const double invf = pow(10000.0, -((double)(2 * p) / 64.0));
  double sd, cd;
  sincos((double)s * invf, &sd, &cd);
  const float val = (j < 32) ? x * (float)cd - partner * (float)sd
                             : x * (float)cd + partner * (float)sd;
  const __hip_bfloat16 hv = __float2bfloat16(val);
  for (int h = 0; h < NH; ++h)
    kh[(size_t)s * QSTRIDE + h * HD + 128 + j] = hv;
}

// ---------------------------------------------------------------------------
// RMS norm (unchanged).
// ---------------------------------------------------------------------------
__global__ __launch_bounds__(256) void rmsnorm_rows_bf16(
    __hip_bfloat16* __restrict__ X, int nrows, float scale) {
  const int row = blockIdx.x * 4 + (threadIdx.x >> 6);
  const int lane = threadIdx.x & 63;
  if (row >= nrows) return;
  __hip_bfloat16* p = X + (size_t)row * HD;
  const float v0 = __bfloat162float(p[lane]);
  const float v1 = __bfloat162float(p[lane + 64]);
  const float v2 = __bfloat162float(p[lane + 128]);
  float ss = v0 * v0 + v1 * v1 + v2 * v2;
#pragma unroll
  for (int off = 32; off > 0; off >>= 1) ss += __shfl_xor(ss, off, 64);
  const float r = scale / sqrtf(ss * (1.0f / 192.0f) + 1.1920929e-7f);
  p[lane] = __float2bfloat16(v0 * r);
  p[lane + 64] = __float2bfloat16(v1 * r);
  p[lane + 128] = __float2bfloat16(v2 * r);
}

// ---------------------------------------------------------------------------
// Flash attention v2: swapped-operand MFMA, BQ=128 (4 waves x 32 q-rows),
// BKV=64. S^T = mfma(K, Qreg): lane holds q=cl for all its kv (kv =
// t*16 + g*4 + r). Softmax: 16-reg reduce + shfl_xor(16,32). P packed bf16
// into per-wave LDS [q][kv]; O^T = mfma(V^T, P): lane keeps q=cl, d =
// dt*16 + g*4 + r -> rescale & 1/l uniform per lane. 2 barriers/step.
// LDS: Ks 64x200 (25.6K) + Vs 128x72 (18.4K) + Ps 4x32x72 (18.4K) = 62.4KB
// -> 2 blocks/CU. Grid 16 x 32 heads = 512 blocks.
// ---------------------------------------------------------------------------
__global__ __launch_bounds__(256, 2) void flash_attn_mfma2(
    const __hip_bfloat16* __restrict__ Qh, const __hip_bfloat16* __restrict__ Kh,
    const __hip_bfloat16* __restrict__ Vtg, const float* __restrict__ mask,
    __hip_bfloat16* __restrict__ O) {
  __shared__ __align__(16) unsigned short Ks[64][200];
  __shared__ __align__(16) unsigned short Vs[128][72];
  __shared__ __align__(16) unsigned short Ps[4][32][72];

  const int tid = threadIdx.x;
  const int wid = tid >> 6, lane = tid & 63;
  const int cl = lane & 15, g = lane >> 4;
  const int h = blockIdx.y;
  const int Q0 = blockIdx.x * 128 + wid * 32;

  const unsigned short* Q = (const unsigned short*)Qh;
  const unsigned short* K = (const unsigned short*)Kh;
  const unsigned short* Vt = (const unsigned short*)Vtg;

  // Q fragments in registers: B-operand, lane holds q-row (Q0+qt*16+cl),
  // k-slice g*8 within chunk c. (q pre-scaled by 1/sqrt(192) in rmsnorm.)
  bf16x8 qreg[2][6];
#pragma unroll
  for (int qt = 0; qt < 2; ++qt)
#pragma unroll
    for (int c = 0; c < 6; ++c)
      qreg[qt][c] = *(const bf16x8*)&Q[(size_t)(Q0 + qt * 16 + cl) * QSTRIDE +
                                       h * HD + c * 32 + g * 8];

  float mprev[2] = {-INFINITY, -INFINITY};
  float lsum[2] = {0.f, 0.f};
  f32x4 acc[2][8] = {};

  for (int k0 = 0; k0 < S_LEN; k0 += 64) {
    __syncthreads();  // all waves done reading Ks/Vs of prev step
    // stage K tile [64][192]: 1536 x 16B chunks
#pragma unroll
    for (int i = 0; i < 6; ++i) {
      const int c = tid + i * 256;
      const int r = c / 24, cc = c % 24;
      *(float4*)&Ks[r][cc * 8] =
          *(const float4*)&K[(size_t)(k0 + r) * QSTRIDE + h * HD + cc * 8];
    }
    // stage V^T tile [128][64]: 1024 chunks
#pragma unroll
    for (int i = 0; i < 4; ++i) {
      const int c = tid + i * 256;
      const int d = c >> 3, jc = c & 7;
      *(float4*)&Vs[d][jc * 8] =
          *(const float4*)&Vt[(size_t)(h * HD_C + d) * S_LEN + k0 + jc * 8];
    }
    __syncthreads();

    // ---- S^T = K * Q^T : s[qt][t] covers kv-tile t, q-tile qt
    f32x4 s[2][4] = {};
#pragma unroll
    for (int t = 0; t < 4; ++t) {
#pragma unroll
      for (int c = 0; c < 6; ++c) {
        const bf16x8 kf = *(const bf16x8*)&Ks[t * 16 + cl][c * 32 + g * 8];
        s[0][t] = __builtin_amdgcn_mfma_f32_16x16x32_bf16(kf, qreg[0][c],
                                                          s[0][t], 0, 0, 0);
        s[1][t] = __builtin_amdgcn_mfma_f32_16x16x32_bf16(kf, qreg[1][c],
                                                          s[1][t], 0, 0, 0);
      }
    }
    // mask add: lane's kv = t*16 + g*4 + r (r contiguous -> float4)
#pragma unroll
    for (int qt = 0; qt < 2; ++qt)
#pragma unroll
      for (int t = 0; t < 4; ++t) {
        const float4 mk = *(const float4*)&mask[(size_t)(Q0 + qt * 16 + cl) *
                                                    S_LEN +
                                                k0 + t * 16 + g * 4];
        s[qt][t][0] += mk.x; s[qt][t][1] += mk.y;
        s[qt][t][2] += mk.z; s[qt][t][3] += mk.w;
      }

    // ---- online softmax, wave-local (lane owns q-row = Q0+qt*16+cl)
#pragma unroll
    for (int qt = 0; qt < 2; ++qt) {
      float mloc = s[qt][0][0];
#pragma unroll
      for (int t = 0; t < 4; ++t)
#pragma unroll
        for (int r = 0; r < 4; ++r) mloc = fmaxf(mloc, s[qt][t][r]);
      mloc = fmaxf(mloc, __shfl_xor(mloc, 16, 64));
      mloc = fmaxf(mloc, __shfl_xor(mloc, 32, 64));
      const float mnew = fmaxf(mprev[qt], mloc);
      const float rsc = __expf(mprev[qt] - mnew);
      mprev[qt] = mnew;
      float p[4][4];
      float ll = 0.f;
#pragma unroll
      for (int t = 0; t < 4; ++t)
#pragma unroll
        for (int r = 0; r < 4; ++r) {
          p[t][r] = __expf(s[qt][t][r] - mnew);
          ll += p[t][r];
        }
      ll += __shfl_xor(ll, 16, 64);
      ll += __shfl_xor(ll, 32, 64);
      lsum[qt] = lsum[qt] * rsc + ll;
#pragma unroll
      for (int dt = 0; dt < 8; ++dt) {
        acc[qt][dt][0] *= rsc; acc[qt][dt][1] *= rsc;
        acc[qt][dt][2] *= rsc; acc[qt][dt][3] *= rsc;
      }
      // pack P row: kv = t*16 + g*4 + (0..3) -> one 8B store per t
#pragma unroll
      for (int t = 0; t < 4; ++t) {
        unsigned short u[4] = {f2bu(p[t][0]), f2bu(p[t][1]), f2bu(p[t][2]),
                               f2bu(p[t][3])};
        *(double*)&Ps[wid][qt * 16 + cl][t * 16 + g * 4] = *(double*)u;
      }
    }

    // ---- O^T += V^T * P  (per-wave P; same-wave ds ordering via lgkmcnt)
#pragma unroll
    for (int c = 0; c < 2; ++c) {
      const bf16x8 pf0 = *(const bf16x8*)&Ps[wid][cl][c * 32 + g * 8];
      const bf16x8 pf1 = *(const bf16x8*)&Ps[wid][16 + cl][c * 32 + g * 8];
#pragma unroll
      for (int dt = 0; dt < 8; ++dt) {
        const bf16x8 vf = *(const bf16x8*)&Vs[dt * 16 + cl][c * 32 + g * 8];
        acc[0][dt] = __builtin_amdgcn_mfma_f32_16x16x32_bf16(vf, pf0,
                                                             acc[0][dt], 0, 0, 0);
        acc[1][dt] = __builtin_amdgcn_mfma_f32_16x16x32_bf16(vf, pf1,
                                                             acc[1][dt], 0, 0, 0);
      }
    }
  }

  // epilogue: lane holds q = Q0+qt*16+cl, d = dt*16 + g*4 + r
#pragma unroll
  for (int qt = 0; qt < 2; ++qt) {
    const float il = 1.0f / lsum[qt];
    const size_t base = (size_t)(Q0 + qt * 16 + cl) * HID + h * HD_C;
#pragma unroll
    for (int dt = 0; dt < 8; ++dt) {
      unsigned short u[4] = {
          f2bu(acc[qt][dt][0] * il), f2bu(acc[qt][dt][1] * il),
          f2bu(acc[qt][dt][2] * il), f2bu(acc[qt][dt][3] * il)};
      *(double*)&((unsigned short*)O)[base + dt * 16 + g * 4] = *(double*)u;
    }
  }
}

// ---------------------------------------------------------------------------
extern "C" void kernel_launch(void* const* d_in, const int* in_sizes, int n_in,
                              void* d_out, int out_size, void* d_ws,
                              size_t ws_size, hipStream_t stream) {
  const float* X       = (const float*)d_in[0];
  const float* mask    = (const float*)d_in[1];
  const float* Wq_lr   = (const float*)d_in[2];
  const float* bq_lr   = (const float*)d_in[3];
  const float* Wq_rope = (const float*)d_in[4];
  const float* bq_rope = (const float*)d_in[5];
  const float* Wq_c    = (const float*)d_in[6];
  const float* bq_c    = (const float*)d_in[7];
  const float* Wkv     = (const float*)d_in[8];
  const float* bkv     = (const float*)d_in[9];
  const float* Wk_rope = (const float*)d_in[10];
  const float* bk_rope = (const float*)d_in[11];
  const float* Wk_c    = (const float*)d_in[12];
  const float* bk_c    = (const float*)d_in[13];
  const float* Wv      = (const float*)d_in[14];
  const float* bv      = (const float*)d_in[15];
  const float* Wo      = (const float*)d_in[16];
  const float* bo      = (const float*)d_in[17];
  float* out = (float*)d_out;

  char* w = (char*)d_ws;
  unsigned short* Xb   = (unsigned short*)w;  w += (size_t)2048 * 4096 * 2;
  unsigned short* wbuf = (unsigned short*)w;  w += (size_t)4096 * 4096 * 2;
  unsigned short* c_qb = (unsigned short*)w;  w += (size_t)2048 * 1536 * 2;
  unsigned short* c_kvb= (unsigned short*)w;  w += (size_t)2048 * 512 * 2;
  float* fb            = (float*)w;           w += (size_t)2048 * 2048 * 4;
  __hip_bfloat16* qh   = (__hip_bfloat16*)w;  w += (size_t)2048 * 6144 * 2;
  __hip_bfloat16* kh   = (__hip_bfloat16*)w;  w += (size_t)2048 * 6144 * 2;
  __hip_bfloat16* vt   = (__hip_bfloat16*)w;  w += (size_t)4096 * 2048 * 2;
  __hip_bfloat16* ob   = (__hip_bfloat16*)fb;  // reuse fb

  const dim3 blk(256);
  auto cvt = [&](const float* s, unsigned short* d, int n) {
    const int n8 = n / 8;
    const int nb = min(2048, (n8 + 255) / 256);
    f32_to_bf16_vec<<<nb, blk, 0, stream>>>(s, d, n8);
  };

  cvt(X, Xb, 2048 * 4096);
  cvt(Wq_lr, wbuf, 1536 * 4096);
  gemm_bf16<<<dim3(12, 16), blk, 0, stream>>>(Xb, wbuf, bq_lr, c_qb,
                                              2048, 1536, 4096, 2, 0);
  cvt(Wq_c, wbuf, 4096 * 1536);
  gemm_bf16<<<dim3(32, 16), blk, 0, stream>>>(c_qb, wbuf, bq_c, qh,
                                              2048, 4096, 1536, 1, 0);
  cvt(Wq_rope, wbuf, 2048 * 1536);
  gemm_bf16<<<dim3(16, 16), blk, 0, stream>>>(c_qb, wbuf, bq_rope, fb,
                                              2048, 2048, 1536, 0, 0);
  rope_scatter_q<<<(S_LEN * 1024) / 256, blk, 0, stream>>>(fb, qh);
  cvt(Wkv, wbuf, 512 * 4096);
  gemm_bf16<<<dim3(4, 16), blk, 0, stream>>>(Xb, wbuf, bkv, c_kvb,
                                             2048, 512, 4096, 2, 0);
  cvt(Wk_c, wbuf, 4096 * 512);
  gemm_bf16<<<dim3(32, 16), blk, 0, stream>>>(c_kvb, wbuf, bk_c, kh,
                                              2048, 4096, 512, 1, 0);
  gemm_bt<16><<<dim3(1, 128), blk, 0, stream>>>(X, Wk_rope, bk_rope, fb,
                                                2048, 64, 4096, 0);
  rope_bcast_k<<<S_LEN, dim3(64), 0, stream>>>(fb, kh);
  cvt(Wv, wbuf, 4096 * 512);
  gemm_bf16<<<dim3(16, 32), blk, 0, stream>>>(wbuf, c_kvb, bv, vt,
                                              4096, 2048, 512, 2, 1);
  rmsnorm_rows_bf16<<<(S_LEN * NH) / 4, blk, 0, stream>>>(
      qh, S_LEN * NH, 0.07216878364870322f);  // 1/sqrt(192)
  rmsnorm_rows_bf16<<<(S_LEN * NH) / 4, blk, 0, stream>>>(kh, S_LEN * NH, 1.0f);
  flash_attn_mfma2<<<dim3(S_LEN / 128, NH), blk, 0, stream>>>(qh, kh, vt, mask,
                                                              ob);
  cvt(Wo, wbuf, 4096 * 4096);
  gemm_bf16<<<dim3(32, 16), blk, 0, stream>>>((const unsigned short*)ob, wbuf,
                                              bo, out, 2048, 4096, 4096, 0, 0);
}

// Round 6
// 993.946 us; speedup vs baseline: 11.5195x; 1.0680x over previous
//
#include <hip/hip_runtime.h>
#include <hip/hip_bf16.h>
#include <math.h>

// MLA round 5 (resubmit after infra timeout): plumbing round.
//  - k_rope projection folded into the c_kv GEMM (combined [640,4096] f32
//    weight, combo epilogue) -> kills the 186us latency-bound gemm_bt.
//  - f32->bf16 weight conversion fused into GEMM staging (template per
//    operand: bf16 -> global_load_lds w16; f32 -> reg-stage + pack +
//    ds_write_b128, same linear LDS layout). Removes 7 convert kernels.
//  - rope trig in f32 (powf + sincosf) matching the reference's own f32 math.
// Flash attention (round-4 swapped-operand kernel) unchanged.

#define S_LEN 2048
#define HID 4096
#define NH 32
#define HD_C 128
#define HD 192
#define QSTRIDE (NH * HD)  // 6144

typedef __bf16 bf16x8 __attribute__((ext_vector_type(8)));
typedef float f32x4 __attribute__((ext_vector_type(4)));

__device__ __forceinline__ unsigned short f2bu(float x) {
  __hip_bfloat16 h = __float2bfloat16(x);
  return *reinterpret_cast<unsigned short*>(&h);
}

// ---------------------------------------------------------------------------
// f32 -> bf16 convert (used only for X).
// ---------------------------------------------------------------------------
__global__ __launch_bounds__(256) void f32_to_bf16_vec(
    const float* __restrict__ src, unsigned short* __restrict__ dst, int n8) {
  for (int i = blockIdx.x * 256 + threadIdx.x; i < n8; i += gridDim.x * 256) {
    const float4 a = ((const float4*)src)[(size_t)i * 2];
    const float4 b = ((const float4*)src)[(size_t)i * 2 + 1];
    unsigned short u[8] = {f2bu(a.x), f2bu(a.y), f2bu(a.z), f2bu(a.w),
                           f2bu(b.x), f2bu(b.y), f2bu(b.z), f2bu(b.w)};
    *(float4*)&dst[(size_t)i * 8] = *(float4*)u;
  }
}

// ---------------------------------------------------------------------------
// Assemble combined kv weight [640][4096] f32 (Wkv | Wk_rope | zeros) and
// combined bias [640].
// ---------------------------------------------------------------------------
__global__ __launch_bounds__(256) void assemble_wkv(
    const float* __restrict__ Wkv, const float* __restrict__ bkv,
    const float* __restrict__ Wk_rope, const float* __restrict__ bk_rope,
    float* __restrict__ Wdst, float* __restrict__ bdst) {
  const int i = blockIdx.x * 256 + threadIdx.x;  // float4 index, row = i>>10
  const int row = i >> 10, c4 = i & 1023;
  float4 v = {0.f, 0.f, 0.f, 0.f};
  if (row < 512)
    v = ((const float4*)Wkv)[(size_t)row * 1024 + c4];
  else if (row < 576)
    v = ((const float4*)Wk_rope)[(size_t)(row - 512) * 1024 + c4];
  ((float4*)Wdst)[i] = v;
  if (blockIdx.x == 0 && threadIdx.x < 160) {
#pragma unroll
    for (int t = 0; t < 4; ++t) {
      const int b = threadIdx.x * 4 + t;
      bdst[b] = b < 512 ? bkv[b] : (b < 576 ? bk_rope[b - 512] : 0.f);
    }
  }
}

// ---------------------------------------------------------------------------
// MFMA GEMM: C[M,N] = A[M,K] @ W[N,K]^T + bias. 128x128 tile, BK=32, 4 waves.
// AF32/BF32: operand dtype in HBM. bf16 -> global_load_lds(16B); f32 ->
// reg-stage 8 floats, pack bf16, ds_write_b128 (same linear LDS layout).
// out_mode: 0 f32 [M,N] | 1 bf16 scatter col->(col>>7)*192+(col&127), row
// stride 6144 | 2 bf16 [M,N] | 3 kv-combo: col<512 -> bf16 Cv[row*512+col],
// 512<=col<576 -> f32 aux[row*64+col-512], else discard.
// bias_mode: 0 bias[col], 1 bias[row].
// ---------------------------------------------------------------------------
template <int AF32, int BF32>
__global__ __launch_bounds__(256) void gemm_mfma(
    const void* __restrict__ Av, const void* __restrict__ Wv_,
    const float* __restrict__ bias, void* __restrict__ Cv,
    int M, int N, int K, int out_mode, int bias_mode,
    float* __restrict__ aux) {
  __shared__ __align__(16) unsigned short As[128 * 32];
  __shared__ __align__(16) unsigned short Bs[128 * 32];

  const int tid = threadIdx.x;
  const int wid = tid >> 6, lane = tid & 63;
  const int cl = lane & 15, g = lane >> 4;
  const int wr = wid >> 1, wc = wid & 1;
  const int m0 = blockIdx.y * 128, n0 = blockIdx.x * 128;

  f32x4 acc[4][4] = {};

  for (int k0 = 0; k0 < K; k0 += 32) {
    __syncthreads();  // previous step's LDS reads complete
    if constexpr (AF32) {
      const float* Af = (const float*)Av;
#pragma unroll
      for (int j = 0; j < 2; ++j) {
        const int c = j * 256 + tid;
        const float* gs = &Af[(size_t)(m0 + (c >> 2)) * K + k0 + (c & 3) * 8];
        const float4 f0 = *(const float4*)gs;
        const float4 f1 = *(const float4*)(gs + 4);
        unsigned short u[8] = {f2bu(f0.x), f2bu(f0.y), f2bu(f0.z), f2bu(f0.w),
                               f2bu(f1.x), f2bu(f1.y), f2bu(f1.z), f2bu(f1.w)};
        *(float4*)&As[(size_t)c * 8] = *(float4*)u;
      }
    } else {
      const unsigned short* Ab = (const unsigned short*)Av;
#pragma unroll
      for (int j = 0; j < 2; ++j) {
        const int c = j * 256 + wid * 64 + lane;
        const unsigned short* ga =
            &Ab[(size_t)(m0 + (c >> 2)) * K + k0 + (c & 3) * 8];
        __builtin_amdgcn_global_load_lds(
            (const __attribute__((address_space(1))) unsigned int*)ga,
            (__attribute__((address_space(3))) unsigned int*)&As[(size_t)(j * 256 + wid * 64) * 8],
            16, 0, 0);
      }
    }
    if constexpr (BF32) {
      const float* Wf = (const float*)Wv_;
#pragma unroll
      for (int j = 0; j < 2; ++j) {
        const int c = j * 256 + tid;
        const float* gs = &Wf[(size_t)(n0 + (c >> 2)) * K + k0 + (c & 3) * 8];
        const float4 f0 = *(const float4*)gs;
        const float4 f1 = *(const float4*)(gs + 4);
        unsigned short u[8] = {f2bu(f0.x), f2bu(f0.y), f2bu(f0.z), f2bu(f0.w),
                               f2bu(f1.x), f2bu(f1.y), f2bu(f1.z), f2bu(f1.w)};
        *(float4*)&Bs[(size_t)c * 8] = *(float4*)u;
      }
    } else {
      const unsigned short* Wb = (const unsigned short*)Wv_;
#pragma unroll
      for (int j = 0; j < 2; ++j) {
        const int c = j * 256 + wid * 64 + lane;
        const unsigned short* gb =
            &Wb[(size_t)(n0 + (c >> 2)) * K + k0 + (c & 3) * 8];
        __builtin_amdgcn_global_load_lds(
            (const __attribute__((address_space(1))) unsigned int*)gb,
            (__attribute__((address_space(3))) unsigned int*)&Bs[(size_t)(j * 256 + wid * 64) * 8],
            16, 0, 0);
      }
    }
    __syncthreads();  // drain vmcnt + lgkmcnt: tiles visible

    bf16x8 a[4], b[4];
#pragma unroll
    for (int m = 0; m < 4; ++m)
      a[m] = *(const bf16x8*)&As[(size_t)(wr * 64 + m * 16 + cl) * 32 + g * 8];
#pragma unroll
    for (int n = 0; n < 4; ++n)
      b[n] = *(const bf16x8*)&Bs[(size_t)(wc * 64 + n * 16 + cl) * 32 + g * 8];
#pragma unroll
    for (int m = 0; m < 4; ++m)
#pragma unroll
      for (int n = 0; n < 4; ++n)
        acc[m][n] =
            __builtin_amdgcn_mfma_f32_16x16x32_bf16(a[m], b[n], acc[m][n], 0, 0, 0);
  }

#pragma unroll
  for (int m = 0; m < 4; ++m) {
    const int row = m0 + wr * 64 + m * 16 + g * 4;
#pragma unroll
    for (int n = 0; n < 4; ++n) {
      const int col = n0 + wc * 64 + n * 16 + cl;
#pragma unroll
      for (int r = 0; r < 4; ++r) {
        const float val =
            acc[m][n][r] + (bias_mode ? bias[row + r] : bias[col]);
        if (out_mode == 0)
          ((float*)Cv)[(size_t)(row + r) * N + col] = val;
        else if (out_mode == 1)
          ((__hip_bfloat16*)Cv)[(size_t)(row + r) * QSTRIDE + (col >> 7) * HD +
                                (col & 127)] = __float2bfloat16(val);
        else if (out_mode == 2)
          ((__hip_bfloat16*)Cv)[(size_t)(row + r) * N + col] =
              __float2bfloat16(val);
        else {  // 3: kv-combo
          if (col < 512)
            ((__hip_bfloat16*)Cv)[(size_t)(row + r) * 512 + col] =
                __float2bfloat16(val);
          else if (col < 576)
            aux[(size_t)(row + r) * 64 + (col - 512)] = val;
        }
      }
    }
  }
}

// ---------------------------------------------------------------------------
// RoPE q: pre f32 [2048,2048]; pair (p, p+1024); f32 trig (matches ref's f32
// angle math). Scatter bf16 into qh[s, (g>>6)*192 + 128 + (g&63)].
// ---------------------------------------------------------------------------
__global__ __launch_bounds__(256) void rope_scatter_q(
    const float* __restrict__ pre, __hip_bfloat16* __restrict__ qh) {
  const int i = blockIdx.x * blockDim.x + threadIdx.x;
  if (i >= S_LEN * 1024) return;
  const int s = i >> 10, p = i & 1023;
  const float invf = powf(10000.0f, -((float)(2 * p) / 2048.0f));
  float sn, cs;
  sincosf((float)s * invf, &sn, &cs);
  const float x1 = pre[(size_t)s * 2048 + p];
  const float x2 = pre[(size_t)s * 2048 + p + 1024];
  const int g1 = p, g2 = p + 1024;
  qh[(size_t)s * QSTRIDE + (g1 >> 6) * HD + 128 + (g1 & 63)] =
      __float2bfloat16(x1 * cs - x2 * sn);
  qh[(size_t)s * QSTRIDE + (g2 >> 6) * HD + 128 + (g2 & 63)] =
      __float2bfloat16(x2 * cs + x1 * sn);
}

// ---------------------------------------------------------------------------
// RoPE k: pre f32 [2048,64]; f32 trig; broadcast bf16 to 32 heads.
// ---------------------------------------------------------------------------
__global__ __launch_bounds__(64) void rope_bcast_k(
    const float* __restrict__ pre, __hip_bfloat16* __restrict__ kh) {
  const int s = blockIdx.x;
  const int j = threadIdx.x;
  const float x = pre[s * 64 + j];
  const float partner = pre[s * 64 + (j ^ 32)];
  const int p = j & 31;
  const float invf = powf(10000.0f, -((float)(2 * p) / 64.0f));
  float sn, cs;
  sincosf((float)s * invf, &sn, &cs);
  const float val = (j < 32) ? x * cs - partner * sn : x * cs + partner * sn;
  const __hip_bfloat16 hv = __float2bfloat16(val);
  for (int h = 0; h < NH; ++h)
    kh[(size_t)s * QSTRIDE + h * HD + 128 + j] = hv;
}

// ---------------------------------------------------------------------------
// RMS norm over 192-dim bf16 rows, in place; optional extra scale folded in.
// ---------------------------------------------------------------------------
__global__ __launch_bounds__(256) void rmsnorm_rows_bf16(
    __hip_bfloat16* __restrict__ X, int nrows, float scale) {
  const int row = blockIdx.x * 4 + (threadIdx.x >> 6);
  const int lane = threadIdx.x & 63;
  if (row >= nrows) return;
  __hip_bfloat16* p = X + (size_t)row * HD;
  const float v0 = __bfloat162float(p[lane]);
  const float v1 = __bfloat162float(p[lane + 64]);
  const float v2 = __bfloat162float(p[lane + 128]);
  float ss = v0 * v0 + v1 * v1 + v2 * v2;
#pragma unroll
  for (int off = 32; off > 0; off >>= 1) ss += __shfl_xor(ss, off, 64);
  const float r = scale / sqrtf(ss * (1.0f / 192.0f) + 1.1920929e-7f);
  p[lane] = __float2bfloat16(v0 * r);
  p[lane + 64] = __float2bfloat16(v1 * r);
  p[lane + 128] = __float2bfloat16(v2 * r);
}

// ---------------------------------------------------------------------------
// Flash attention v2 (unchanged from round 4): swapped-operand MFMA,
// BQ=128 (4 waves x 32 q-rows), BKV=64, wave-local softmax, 2 barriers/step.
// ---------------------------------------------------------------------------
__global__ __launch_bounds__(256, 2) void flash_attn_mfma2(
    const __hip_bfloat16* __restrict__ Qh, const __hip_bfloat16* __restrict__ Kh,
    const __hip_bfloat16* __restrict__ Vtg, const float* __restrict__ mask,
    __hip_bfloat16* __restrict__ O) {
  __shared__ __align__(16) unsigned short Ks[64][200];
  __shared__ __align__(16) unsigned short Vs[128][72];
  __shared__ __align__(16) unsigned short Ps[4][32][72];

  const int tid = threadIdx.x;
  const int wid = tid >> 6, lane = tid & 63;
  const int cl = lane & 15, g = lane >> 4;
  const int h = blockIdx.y;
  const int Q0 = blockIdx.x * 128 + wid * 32;

  const unsigned short* Q = (const unsigned short*)Qh;
  const unsigned short* K = (const unsigned short*)Kh;
  const unsigned short* Vt = (const unsigned short*)Vtg;

  bf16x8 qreg[2][6];
#pragma unroll
  for (int qt = 0; qt < 2; ++qt)
#pragma unroll
    for (int c = 0; c < 6; ++c)
      qreg[qt][c] = *(const bf16x8*)&Q[(size_t)(Q0 + qt * 16 + cl) * QSTRIDE +
                                       h * HD + c * 32 + g * 8];

  float mprev[2] = {-INFINITY, -INFINITY};
  float lsum[2] = {0.f, 0.f};
  f32x4 acc[2][8] = {};

  for (int k0 = 0; k0 < S_LEN; k0 += 64) {
    __syncthreads();
#pragma unroll
    for (int i = 0; i < 6; ++i) {
      const int c = tid + i * 256;
      const int r = c / 24, cc = c % 24;
      *(float4*)&Ks[r][cc * 8] =
          *(const float4*)&K[(size_t)(k0 + r) * QSTRIDE + h * HD + cc * 8];
    }
#pragma unroll
    for (int i = 0; i < 4; ++i) {
      const int c = tid + i * 256;
      const int d = c >> 3, jc = c & 7;
      *(float4*)&Vs[d][jc * 8] =
          *(const float4*)&Vt[(size_t)(h * HD_C + d) * S_LEN + k0 + jc * 8];
    }
    __syncthreads();

    f32x4 s[2][4] = {};
#pragma unroll
    for (int t = 0; t < 4; ++t) {
#pragma unroll
      for (int c = 0; c < 6; ++c) {
        const bf16x8 kf = *(const bf16x8*)&Ks[t * 16 + cl][c * 32 + g * 8];
        s[0][t] = __builtin_amdgcn_mfma_f32_16x16x32_bf16(kf, qreg[0][c],
                                                          s[0][t], 0, 0, 0);
        s[1][t] = __builtin_amdgcn_mfma_f32_16x16x32_bf16(kf, qreg[1][c],
                                                          s[1][t], 0, 0, 0);
      }
    }
#pragma unroll
    for (int qt = 0; qt < 2; ++qt)
#pragma unroll
      for (int t = 0; t < 4; ++t) {
        const float4 mk = *(const float4*)&mask[(size_t)(Q0 + qt * 16 + cl) *
                                                    S_LEN +
                                                k0 + t * 16 + g * 4];
        s[qt][t][0] += mk.x; s[qt][t][1] += mk.y;
        s[qt][t][2] += mk.z; s[qt][t][3] += mk.w;
      }

#pragma unroll
    for (int qt = 0; qt < 2; ++qt) {
      float mloc = s[qt][0][0];
#pragma unroll
      for (int t = 0; t < 4; ++t)
#pragma unroll
        for (int r = 0; r < 4; ++r) mloc = fmaxf(mloc, s[qt][t][r]);
      mloc = fmaxf(mloc, __shfl_xor(mloc, 16, 64));
      mloc = fmaxf(mloc, __shfl_xor(mloc, 32, 64));
      const float mnew = fmaxf(mprev[qt], mloc);
      const float rsc = __expf(mprev[qt] - mnew);
      mprev[qt] = mnew;
      float p[4][4];
      float ll = 0.f;
#pragma unroll
      for (int t = 0; t < 4; ++t)
#pragma unroll
        for (int r = 0; r < 4; ++r) {
          p[t][r] = __expf(s[qt][t][r] - mnew);
          ll += p[t][r];
        }
      ll += __shfl_xor(ll, 16, 64);
      ll += __shfl_xor(ll, 32, 64);
      lsum[qt] = lsum[qt] * rsc + ll;
#pragma unroll
      for (int dt = 0; dt < 8; ++dt) {
        acc[qt][dt][0] *= rsc; acc[qt][dt][1] *= rsc;
        acc[qt][dt][2] *= rsc; acc[qt][dt][3] *= rsc;
      }
#pragma unroll
      for (int t = 0; t < 4; ++t) {
        unsigned short u[4] = {f2bu(p[t][0]), f2bu(p[t][1]), f2bu(p[t][2]),
                               f2bu(p[t][3])};
        *(double*)&Ps[wid][qt * 16 + cl][t * 16 + g * 4] = *(double*)u;
      }
    }

#pragma unroll
    for (int c = 0; c < 2; ++c) {
      const bf16x8 pf0 = *(const bf16x8*)&Ps[wid][cl][c * 32 + g * 8];
      const bf16x8 pf1 = *(const bf16x8*)&Ps[wid][16 + cl][c * 32 + g * 8];
#pragma unroll
      for (int dt = 0; dt < 8; ++dt) {
        const bf16x8 vf = *(const bf16x8*)&Vs[dt * 16 + cl][c * 32 + g * 8];
        acc[0][dt] = __builtin_amdgcn_mfma_f32_16x16x32_bf16(vf, pf0,
                                                             acc[0][dt], 0, 0, 0);
        acc[1][dt] = __builtin_amdgcn_mfma_f32_16x16x32_bf16(vf, pf1,
                                                             acc[1][dt], 0, 0, 0);
      }
    }
  }

#pragma unroll
  for (int qt = 0; qt < 2; ++qt) {
    const float il = 1.0f / lsum[qt];
    const size_t base = (size_t)(Q0 + qt * 16 + cl) * HID + h * HD_C;
#pragma unroll
    for (int dt = 0; dt < 8; ++dt) {
      unsigned short u[4] = {
          f2bu(acc[qt][dt][0] * il), f2bu(acc[qt][dt][1] * il),
          f2bu(acc[qt][dt][2] * il), f2bu(acc[qt][dt][3] * il)};
      *(double*)&((unsigned short*)O)[base + dt * 16 + g * 4] = *(double*)u;
    }
  }
}

// ---------------------------------------------------------------------------
extern "C" void kernel_launch(void* const* d_in, const int* in_sizes, int n_in,
                              void* d_out, int out_size, void* d_ws,
                              size_t ws_size, hipStream_t stream) {
  const float* X       = (const float*)d_in[0];
  const float* mask    = (const float*)d_in[1];
  const float* Wq_lr   = (const float*)d_in[2];
  const float* bq_lr   = (const float*)d_in[3];
  const float* Wq_rope = (const float*)d_in[4];
  const float* bq_rope = (const float*)d_in[5];
  const float* Wq_c    = (const float*)d_in[6];
  const float* bq_c    = (const float*)d_in[7];
  const float* Wkv     = (const float*)d_in[8];
  const float* bkv     = (const float*)d_in[9];
  const float* Wk_rope = (const float*)d_in[10];
  const float* bk_rope = (const float*)d_in[11];
  const float* Wk_c    = (const float*)d_in[12];
  const float* bk_c    = (const float*)d_in[13];
  const float* Wv      = (const float*)d_in[14];
  const float* bv      = (const float*)d_in[15];
  const float* Wo      = (const float*)d_in[16];
  const float* bo      = (const float*)d_in[17];
  float* out = (float*)d_out;

  char* w = (char*)d_ws;
  unsigned short* Xb   = (unsigned short*)w;  w += (size_t)2048 * 4096 * 2;
  float* wkvf          = (float*)w;           w += (size_t)640 * 4096 * 4;
  float* bkvf          = (float*)w;           w += 4096;  // 640 f32 + pad
  unsigned short* c_qb = (unsigned short*)w;  w += (size_t)2048 * 1536 * 2;
  unsigned short* c_kvb= (unsigned short*)w;  w += (size_t)2048 * 512 * 2;
  float* fb            = (float*)w;           w += (size_t)2048 * 2048 * 4;
  float* fbk           = (float*)w;           w += (size_t)2048 * 64 * 4;
  __hip_bfloat16* qh   = (__hip_bfloat16*)w;  w += (size_t)2048 * 6144 * 2;
  __hip_bfloat16* kh   = (__hip_bfloat16*)w;  w += (size_t)2048 * 6144 * 2;
  __hip_bfloat16* vt   = (__hip_bfloat16*)w;  w += (size_t)4096 * 2048 * 2;
  __hip_bfloat16* ob   = (__hip_bfloat16*)fb;  // reuse fb (both 16.8MB)

  const dim3 blk(256);

  // X -> bf16 (only remaining standalone convert)
  f32_to_bf16_vec<<<2048, blk, 0, stream>>>(X, Xb, 2048 * 4096 / 8);
  // combined kv weight + bias
  assemble_wkv<<<2560, blk, 0, stream>>>(Wkv, bkv, Wk_rope, bk_rope, wkvf,
                                         bkvf);
  // 1. c_q = X @ Wq_lr^T (bf16 out)
  gemm_mfma<0, 1><<<dim3(12, 16), blk, 0, stream>>>(
      Xb, Wq_lr, bq_lr, c_qb, 2048, 1536, 4096, 2, 0, nullptr);
  // 2. q_content -> qh (scatter)
  gemm_mfma<0, 1><<<dim3(32, 16), blk, 0, stream>>>(
      c_qb, Wq_c, bq_c, qh, 2048, 4096, 1536, 1, 0, nullptr);
  // 3. q_rope pre -> fb (f32); rope -> qh
  gemm_mfma<0, 1><<<dim3(16, 16), blk, 0, stream>>>(
      c_qb, Wq_rope, bq_rope, fb, 2048, 2048, 1536, 0, 0, nullptr);
  rope_scatter_q<<<(S_LEN * 1024) / 256, blk, 0, stream>>>(fb, qh);
  // 4. kv-combo: c_kv -> c_kvb (bf16), k_rope pre -> fbk (f32)
  gemm_mfma<0, 1><<<dim3(5, 16), blk, 0, stream>>>(
      Xb, wkvf, bkvf, c_kvb, 2048, 640, 4096, 3, 0, fbk);
  rope_bcast_k<<<S_LEN, dim3(64), 0, stream>>>(fbk, kh);
  // 5. k_content -> kh (scatter)
  gemm_mfma<0, 1><<<dim3(32, 16), blk, 0, stream>>>(
      c_kvb, Wk_c, bk_c, kh, 2048, 4096, 512, 1, 0, nullptr);
  // 6. vt[d,s] = Wv @ c_kv^T + bv[d]  (A = f32 weights)
  gemm_mfma<1, 0><<<dim3(16, 32), blk, 0, stream>>>(
      Wv, c_kvb, bv, vt, 4096, 2048, 512, 2, 1, nullptr);
  // 7. RMS norm q (x 1/sqrt(192)), k
  rmsnorm_rows_bf16<<<(S_LEN * NH) / 4, blk, 0, stream>>>(
      qh, S_LEN * NH, 0.07216878364870322f);
  rmsnorm_rows_bf16<<<(S_LEN * NH) / 4, blk, 0, stream>>>(kh, S_LEN * NH, 1.0f);
  // 8. attention -> ob (bf16, overlays fb)
  flash_attn_mfma2<<<dim3(S_LEN / 128, NH), blk, 0, stream>>>(qh, kh, vt, mask,
                                                              ob);
  // 9. out = ob @ Wo^T + bo (f32)
  gemm_mfma<0, 1><<<dim3(32, 16), blk, 0, stream>>>(
      (const unsigned short*)ob, Wo, bo, out, 2048, 4096, 4096, 0, 0, nullptr);
}